// Round 3
// baseline (3539.193 us; speedup 1.0000x reference)
//
#include <hip/hip_runtime.h>

#define BATCH 8
#define NPTS  2048
#define KNN   20
#define M1    (BATCH * NPTS * KNN)   // 327680 rows for conv stages
#define M5    (BATCH * NPTS)         // 16384 rows for final projection
#define EPSBN 1e-5f

typedef unsigned short bf16_t;

__device__ __forceinline__ float bf2f(bf16_t u) {
    return __uint_as_float(((unsigned int)u) << 16);
}
__device__ __forceinline__ bf16_t f2bf(float f) {
    unsigned int u = __float_as_uint(f);
    return (bf16_t)((u + 0x7fffu + ((u >> 16) & 1u)) >> 16);
}
__device__ __forceinline__ float lrelu(float v) { return v >= 0.f ? v : 0.2f * v; }

// ---------------------------------------------------------------------------
// KNN — bit-exact replication of the numpy fp32 reference arithmetic:
//   inner = (x0n*x0m + x1n*x1m) + x2n*x2m        (fp32, no FMA, c-order)
//   xx    = (x0^2 + x1^2) + x2^2                  (fp32, no FMA)
//   pdist = (2*inner - xx_n) - xx_m               (fp32, left-to-right)
// Top-20 by strict '>' insertion: ties keep the earlier (lower) index,
// matching lax.top_k's stable tie-break. Downstream only the neighbor SET
// matters (max-over-k + sums are order-invariant).
// ---------------------------------------------------------------------------
__global__ __launch_bounds__(256) void knn_kernel(const float* __restrict__ x,
                                                  int* __restrict__ idx)
{
    __shared__ float xs0[NPTS], xs1[NPTS], xs2[NPTS];
    __shared__ float xxs[NPTS];
    int t = threadIdx.x;
    int b = blockIdx.x >> 3;          // 8 blocks per batch
    int chunk = blockIdx.x & 7;
    const float* xb = x + (size_t)b * 3 * NPTS;
    for (int i = t; i < NPTS; i += 256) {
        float a0 = xb[i], a1 = xb[NPTS + i], a2 = xb[2 * NPTS + i];
        xs0[i] = a0; xs1[i] = a1; xs2[i] = a2;
        xxs[i] = __fadd_rn(__fadd_rn(__fmul_rn(a0, a0), __fmul_rn(a1, a1)),
                           __fmul_rn(a2, a2));
    }
    __syncthreads();
    int n = chunk * 256 + t;
    float xn0 = xs0[n], xn1 = xs1[n], xn2 = xs2[n];
    float xxn = xxs[n];
    float bd[KNN];
    int   bi[KNN];
#pragma unroll
    for (int i = 0; i < KNN; ++i) { bd[i] = -3e38f; bi[i] = 0; }
    for (int m = 0; m < NPTS; ++m) {
        float inner = __fadd_rn(__fadd_rn(__fmul_rn(xn0, xs0[m]),
                                          __fmul_rn(xn1, xs1[m])),
                                __fmul_rn(xn2, xs2[m]));
        float d = __fsub_rn(__fsub_rn(__fmul_rn(2.0f, inner), xxn), xxs[m]);
        if (d > bd[KNN - 1]) {
            int p = KNN - 1;
            while (p > 0 && bd[p - 1] < d) {   // strict: equal keeps earlier index
                bd[p] = bd[p - 1]; bi[p] = bi[p - 1]; --p;
            }
            bd[p] = d; bi[p] = m;
        }
    }
    int* op = idx + (size_t)(b * NPTS + n) * KNN;
#pragma unroll
    for (int i = 0; i < KNN; ++i) op[i] = bi[i];
}

// ---------------------------------------------------------------------------
// conv1: gather edge features [xj-xi, xi] (6ch), multiply by W1 [64,6].
// Writes y1 [M1,64] bf16 + bucketed (sum,sumsq) stats via atomics.
// ---------------------------------------------------------------------------
__global__ __launch_bounds__(256) void conv1_kernel(const float* __restrict__ x,
                                                    const int* __restrict__ idx,
                                                    const float* __restrict__ W1,
                                                    bf16_t* __restrict__ Y,
                                                    float* __restrict__ st)
{
    __shared__ float f[64][6];
    __shared__ float w[384];
    __shared__ float red[256];
    int t = threadIdx.x;
    for (int i = t; i < 384; i += 256) w[i] = W1[i];
    int row0 = blockIdx.x * 64;
    if (t < 64) {
        int gr = row0 + t;
        int bn = gr / KNN;
        int j = idx[gr];
        int b = bn >> 11, n = bn & (NPTS - 1);
        const float* xb = x + (size_t)b * 3 * NPTS;
        float xi0 = xb[n], xi1 = xb[NPTS + n], xi2 = xb[2 * NPTS + n];
        float xj0 = xb[j], xj1 = xb[NPTS + j], xj2 = xb[2 * NPTS + j];
        f[t][0] = xj0 - xi0; f[t][1] = xj1 - xi1; f[t][2] = xj2 - xi2;
        f[t][3] = xi0;       f[t][4] = xi1;       f[t][5] = xi2;
    }
    __syncthreads();
    int tx = t & 63, ty = t >> 6;
    float wc0 = w[tx * 6 + 0], wc1 = w[tx * 6 + 1], wc2 = w[tx * 6 + 2];
    float wc3 = w[tx * 6 + 3], wc4 = w[tx * 6 + 4], wc5 = w[tx * 6 + 5];
    float ssum = 0.f, ssq = 0.f;
#pragma unroll
    for (int i = 0; i < 16; ++i) {
        int r = ty * 16 + i;
        float yv = f[r][0] * wc0 + f[r][1] * wc1 + f[r][2] * wc2 +
                   f[r][3] * wc3 + f[r][4] * wc4 + f[r][5] * wc5;
        Y[(size_t)(row0 + r) * 64 + tx] = f2bf(yv);
        ssum += yv; ssq += yv * yv;
    }
    int bucket = blockIdx.x & 63;
    red[ty * 64 + tx] = ssum;
    __syncthreads();
    if (t < 64) {
        float v = red[t] + red[64 + t] + red[128 + t] + red[192 + t];
        atomicAdd(&st[bucket * 128 + t], v);
    }
    __syncthreads();
    red[ty * 64 + tx] = ssq;
    __syncthreads();
    if (t < 64) {
        float v = red[t] + red[64 + t] + red[128 + t] + red[192 + t];
        atomicAdd(&st[bucket * 128 + 64 + t], v);
    }
}

// ---------------------------------------------------------------------------
// Generic fused GEMM on bf16 A: Y[M,Nout](bf16) = act(A)[M,K] * W[Nout,K]^T
//   act(a) = leaky_relu(a*sIn[k]+tIn[k]) if sIn, else identity.
// Y==nullptr -> stats-only pass. Stats: 64-bucket (sum,sumsq) atomics.
// 64x64 tile, 256 threads, 4x4 micro-tile, K-chunk 16.
// ---------------------------------------------------------------------------
__global__ __launch_bounds__(256) void gemm_bn_bf16(const bf16_t* __restrict__ A,
                                                    const float* __restrict__ W,
                                                    const float* __restrict__ sIn,
                                                    const float* __restrict__ tIn,
                                                    bf16_t* __restrict__ Y,
                                                    float* __restrict__ st,
                                                    int M, int K, int Nout)
{
    __shared__ float As[16][64];
    __shared__ float Bs[16][64];
    int t = threadIdx.x;
    int tx = t & 15, ty = t >> 4;
    size_t row0 = (size_t)blockIdx.x * 64;
    int col0 = blockIdx.y * 64;
    int lm = t >> 2, lk = (t & 3) * 4;
    float acc[4][4] = {};
    const bf16_t* Ap = A + (row0 + lm) * K + lk;
    const float* Wp = W + (size_t)(col0 + lm) * K + lk;
    for (int k0 = 0; k0 < K; k0 += 16) {
        ushort4 au = *(const ushort4*)(Ap + k0);
        float4 av = make_float4(bf2f(au.x), bf2f(au.y), bf2f(au.z), bf2f(au.w));
        if (sIn) {
            float4 sv = *(const float4*)(sIn + k0 + lk);
            float4 tv = *(const float4*)(tIn + k0 + lk);
            av.x = lrelu(fmaf(av.x, sv.x, tv.x));
            av.y = lrelu(fmaf(av.y, sv.y, tv.y));
            av.z = lrelu(fmaf(av.z, sv.z, tv.z));
            av.w = lrelu(fmaf(av.w, sv.w, tv.w));
        }
        As[lk + 0][lm] = av.x; As[lk + 1][lm] = av.y;
        As[lk + 2][lm] = av.z; As[lk + 3][lm] = av.w;
        float4 bv = *(const float4*)(Wp + k0);
        Bs[lk + 0][lm] = bv.x; Bs[lk + 1][lm] = bv.y;
        Bs[lk + 2][lm] = bv.z; Bs[lk + 3][lm] = bv.w;
        __syncthreads();
#pragma unroll
        for (int kk = 0; kk < 16; ++kk) {
            float4 a4 = *(const float4*)&As[kk][ty * 4];
            float4 b4 = *(const float4*)&Bs[kk][tx * 4];
            float a[4] = { a4.x, a4.y, a4.z, a4.w };
            float bb[4] = { b4.x, b4.y, b4.z, b4.w };
#pragma unroll
            for (int i = 0; i < 4; ++i)
#pragma unroll
                for (int j = 0; j < 4; ++j)
                    acc[i][j] = fmaf(a[i], bb[j], acc[i][j]);
        }
        __syncthreads();
    }
    if (Y) {
#pragma unroll
        for (int i = 0; i < 4; ++i) {
            ushort4 o;
            o.x = f2bf(acc[i][0]); o.y = f2bf(acc[i][1]);
            o.z = f2bf(acc[i][2]); o.w = f2bf(acc[i][3]);
            *(ushort4*)&Y[(row0 + ty * 4 + i) * Nout + col0 + tx * 4] = o;
        }
    }
    __syncthreads();
    float* red = &As[0][0];
    int bucket = blockIdx.x & 63;
    float p0[4], p1[4];
#pragma unroll
    for (int j = 0; j < 4; ++j) {
        p0[j] = acc[0][j] + acc[1][j] + acc[2][j] + acc[3][j];
        p1[j] = acc[0][j] * acc[0][j] + acc[1][j] * acc[1][j] +
                acc[2][j] * acc[2][j] + acc[3][j] * acc[3][j];
    }
#pragma unroll
    for (int j = 0; j < 4; ++j) red[ty * 64 + tx * 4 + j] = p0[j];
    __syncthreads();
    if (t < 64) {
        float v = 0.f;
#pragma unroll
        for (int r = 0; r < 16; ++r) v += red[r * 64 + t];
        atomicAdd(&st[(size_t)bucket * 2 * Nout + col0 + t], v);
    }
    __syncthreads();
#pragma unroll
    for (int j = 0; j < 4; ++j) red[ty * 64 + tx * 4 + j] = p1[j];
    __syncthreads();
    if (t < 64) {
        float v = 0.f;
#pragma unroll
        for (int r = 0; r < 16; ++r) v += red[r * 64 + t];
        atomicAdd(&st[(size_t)bucket * 2 * Nout + Nout + col0 + t], v);
    }
}

// ---------------------------------------------------------------------------
// Stage-4 fused pass 2: y4 never materialized. 80-row tile = exactly 4 points
// (4*20 edges). Computes y4 tile, applies BN+LReLU (s4,t4 known from pass 1),
// max-over-k in LDS, writes cat slab4 [M5,256] directly.
// ---------------------------------------------------------------------------
__global__ __launch_bounds__(256) void gemm4_fused(const bf16_t* __restrict__ A,
                                                   const float* __restrict__ W,
                                                   const float* __restrict__ s3,
                                                   const float* __restrict__ t3,
                                                   const float* __restrict__ s4,
                                                   const float* __restrict__ t4,
                                                   float* __restrict__ slab4)
{
    const int K = 128;
    __shared__ float As[16][80];
    __shared__ float Bs[16][64];
    __shared__ float tile[80][65];
    int t = threadIdx.x;
    int row0 = blockIdx.x * 80;       // 4096 blocks: 4 points each
    int col0 = blockIdx.y * 64;       // 4 col tiles
    int tx = t & 15, ty = t >> 4;     // cols tx*4.., rows ty*5..
    float acc[5][4] = {};
    int lmB = t >> 2, lkB = (t & 3) * 4;
    const float* Wp = W + (size_t)(col0 + lmB) * K + lkB;
    for (int k0 = 0; k0 < K; k0 += 16) {
        for (int i = t; i < 320; i += 256) {
            int r = i >> 2, kq = (i & 3) * 4;
            int kc = k0 + kq;
            ushort4 au = *(const ushort4*)(A + (size_t)(row0 + r) * K + kc);
            float4 sv = *(const float4*)(s3 + kc);
            float4 tv = *(const float4*)(t3 + kc);
            As[kq + 0][r] = lrelu(fmaf(bf2f(au.x), sv.x, tv.x));
            As[kq + 1][r] = lrelu(fmaf(bf2f(au.y), sv.y, tv.y));
            As[kq + 2][r] = lrelu(fmaf(bf2f(au.z), sv.z, tv.z));
            As[kq + 3][r] = lrelu(fmaf(bf2f(au.w), sv.w, tv.w));
        }
        float4 bv = *(const float4*)(Wp + k0);
        Bs[lkB + 0][lmB] = bv.x; Bs[lkB + 1][lmB] = bv.y;
        Bs[lkB + 2][lmB] = bv.z; Bs[lkB + 3][lmB] = bv.w;
        __syncthreads();
#pragma unroll
        for (int kk = 0; kk < 16; ++kk) {
            float4 b4 = *(const float4*)&Bs[kk][tx * 4];
            float ar[5];
#pragma unroll
            for (int i = 0; i < 5; ++i) ar[i] = As[kk][ty * 5 + i];
            float bb[4] = { b4.x, b4.y, b4.z, b4.w };
#pragma unroll
            for (int i = 0; i < 5; ++i)
#pragma unroll
                for (int j = 0; j < 4; ++j)
                    acc[i][j] = fmaf(ar[i], bb[j], acc[i][j]);
        }
        __syncthreads();
    }
    float s4c[4], t4c[4];
#pragma unroll
    for (int j = 0; j < 4; ++j) {
        s4c[j] = s4[col0 + tx * 4 + j];
        t4c[j] = t4[col0 + tx * 4 + j];
    }
#pragma unroll
    for (int i = 0; i < 5; ++i)
#pragma unroll
        for (int j = 0; j < 4; ++j)
            tile[ty * 5 + i][tx * 4 + j] = lrelu(fmaf(acc[i][j], s4c[j], t4c[j]));
    __syncthreads();
    int pt = t >> 6, col = t & 63;
    float m = -1e30f;
#pragma unroll
    for (int k = 0; k < KNN; ++k) m = fmaxf(m, tile[pt * KNN + k][col]);
    int point = blockIdx.x * 4 + pt;
    slab4[(size_t)point * 256 + col0 + col] = m;
}

// ---------------------------------------------------------------------------
// Final GEMM: y5[M5,1024] = cat[M5,512] * W5^T, cat gathered from 4 slabs.
// ---------------------------------------------------------------------------
__global__ __launch_bounds__(256) void gemm5_kernel(const float* __restrict__ c1,
                                                    const float* __restrict__ c2,
                                                    const float* __restrict__ c3,
                                                    const float* __restrict__ c4,
                                                    const float* __restrict__ W,
                                                    float* __restrict__ Y,
                                                    float* __restrict__ st)
{
    const int K = 512, Nout = 1024;
    __shared__ float As[16][64];
    __shared__ float Bs[16][64];
    int t = threadIdx.x;
    int tx = t & 15, ty = t >> 4;
    size_t row0 = (size_t)blockIdx.x * 64;
    int col0 = blockIdx.y * 64;
    int lm = t >> 2, lk = (t & 3) * 4;
    float acc[4][4] = {};
    size_t row = row0 + lm;
    const float* Wp = W + (size_t)(col0 + lm) * K + lk;
    for (int k0 = 0; k0 < K; k0 += 16) {
        int kk0 = k0 + lk;
        const float* sp;
        if (kk0 < 64)       sp = c1 + row * 64  + kk0;
        else if (kk0 < 128) sp = c2 + row * 64  + (kk0 - 64);
        else if (kk0 < 256) sp = c3 + row * 128 + (kk0 - 128);
        else                sp = c4 + row * 256 + (kk0 - 256);
        float4 av = *(const float4*)sp;
        As[lk + 0][lm] = av.x; As[lk + 1][lm] = av.y;
        As[lk + 2][lm] = av.z; As[lk + 3][lm] = av.w;
        float4 bv = *(const float4*)(Wp + k0);
        Bs[lk + 0][lm] = bv.x; Bs[lk + 1][lm] = bv.y;
        Bs[lk + 2][lm] = bv.z; Bs[lk + 3][lm] = bv.w;
        __syncthreads();
#pragma unroll
        for (int kk = 0; kk < 16; ++kk) {
            float4 a4 = *(const float4*)&As[kk][ty * 4];
            float4 b4 = *(const float4*)&Bs[kk][tx * 4];
            float a[4] = { a4.x, a4.y, a4.z, a4.w };
            float bb[4] = { b4.x, b4.y, b4.z, b4.w };
#pragma unroll
            for (int i = 0; i < 4; ++i)
#pragma unroll
                for (int j = 0; j < 4; ++j)
                    acc[i][j] = fmaf(a[i], bb[j], acc[i][j]);
        }
        __syncthreads();
    }
#pragma unroll
    for (int i = 0; i < 4; ++i) {
        float4 v = make_float4(acc[i][0], acc[i][1], acc[i][2], acc[i][3]);
        *(float4*)&Y[(row0 + ty * 4 + i) * Nout + col0 + tx * 4] = v;
    }
    __syncthreads();
    float* red = &As[0][0];
    int bucket = blockIdx.x & 63;
    float p0[4], p1[4];
#pragma unroll
    for (int j = 0; j < 4; ++j) {
        p0[j] = acc[0][j] + acc[1][j] + acc[2][j] + acc[3][j];
        p1[j] = acc[0][j] * acc[0][j] + acc[1][j] * acc[1][j] +
                acc[2][j] * acc[2][j] + acc[3][j] * acc[3][j];
    }
#pragma unroll
    for (int j = 0; j < 4; ++j) red[ty * 64 + tx * 4 + j] = p0[j];
    __syncthreads();
    if (t < 64) {
        float v = 0.f;
#pragma unroll
        for (int r = 0; r < 16; ++r) v += red[r * 64 + t];
        atomicAdd(&st[(size_t)bucket * 2 * Nout + col0 + t], v);
    }
    __syncthreads();
#pragma unroll
    for (int j = 0; j < 4; ++j) red[ty * 64 + tx * 4 + j] = p1[j];
    __syncthreads();
    if (t < 64) {
        float v = 0.f;
#pragma unroll
        for (int r = 0; r < 16; ++r) v += red[r * 64 + t];
        atomicAdd(&st[(size_t)bucket * 2 * Nout + Nout + col0 + t], v);
    }
}

// ---------------------------------------------------------------------------
__global__ void finalize_kernel(const float* __restrict__ st,
                                const float* __restrict__ g,
                                const float* __restrict__ bb,
                                float* __restrict__ s, float* __restrict__ tt,
                                int C, float invM)
{
    int c = blockIdx.x * blockDim.x + threadIdx.x;
    if (c >= C) return;
    float sum = 0.f, sq = 0.f;
    for (int bk = 0; bk < 64; ++bk) {
        sum += st[(size_t)bk * 2 * C + c];
        sq  += st[(size_t)bk * 2 * C + C + c];
    }
    float mu  = sum * invM;
    float var = sq * invM - mu * mu;
    float sc  = g[c] * rsqrtf(var + EPSBN);
    s[c]  = sc;
    tt[c] = bb[c] - mu * sc;
}

// ---------------------------------------------------------------------------
// Max over k of leaky_relu(y*s+t) -> one cat slab [M5, C].
// ---------------------------------------------------------------------------
__global__ __launch_bounds__(256) void maxk_kernel(const bf16_t* __restrict__ Y,
                                                   const float* __restrict__ s,
                                                   const float* __restrict__ tt,
                                                   float* __restrict__ slab,
                                                   int C, int logC)
{
    int gid = blockIdx.x * 256 + threadIdx.x;
    int c = gid & (C - 1);
    int bn = gid >> logC;
    float sc = s[c], tc = tt[c];
    const bf16_t* p = Y + (size_t)bn * KNN * C + c;
    float m = -1e30f;
#pragma unroll
    for (int kk = 0; kk < KNN; ++kk) {
        float v = fmaf(bf2f(p[(size_t)kk * C]), sc, tc);
        m = fmaxf(m, lrelu(v));
    }
    slab[(size_t)bn * C + c] = m;
}

// ---------------------------------------------------------------------------
// Output: BN+LeakyReLU on y5 [B*N,1024], transposed write -> out [B,1024,N].
// ---------------------------------------------------------------------------
__global__ __launch_bounds__(256) void out_kernel(const float* __restrict__ y5,
                                                  const float* __restrict__ s,
                                                  const float* __restrict__ tt,
                                                  float* __restrict__ out)
{
    __shared__ float tile[32][65];
    int t = threadIdx.x;
    int b = blockIdx.z;
    int o0 = blockIdx.y * 32;
    int n0 = blockIdx.x * 64;
#pragma unroll
    for (int p = 0; p < 8; ++p) {
        int ol = t & 31, nl = (t >> 5) + 8 * p;
        tile[ol][nl] = y5[((size_t)b * NPTS + n0 + nl) * 1024 + o0 + ol];
    }
    __syncthreads();
#pragma unroll
    for (int p = 0; p < 8; ++p) {
        int nl = t & 63, ol = (t >> 6) + 4 * p;
        float v = fmaf(tile[ol][nl], s[o0 + ol], tt[o0 + ol]);
        out[(size_t)b * 1024 * NPTS + (size_t)(o0 + ol) * NPTS + n0 + nl] = lrelu(v);
    }
}

// ---------------------------------------------------------------------------
extern "C" void kernel_launch(void* const* d_in, const int* in_sizes, int n_in,
                              void* d_out, int out_size, void* d_ws, size_t ws_size,
                              hipStream_t stream)
{
    const float* x  = (const float*)d_in[0];
    const float* W1 = (const float*)d_in[1];
    const float* g1 = (const float*)d_in[2];  const float* b1 = (const float*)d_in[3];
    const float* W2 = (const float*)d_in[4];
    const float* g2 = (const float*)d_in[5];  const float* b2 = (const float*)d_in[6];
    const float* W3 = (const float*)d_in[7];
    const float* g3 = (const float*)d_in[8];  const float* b3 = (const float*)d_in[9];
    const float* W4 = (const float*)d_in[10];
    const float* g4 = (const float*)d_in[11]; const float* b4 = (const float*)d_in[12];
    const float* W5 = (const float*)d_in[13];
    const float* g5 = (const float*)d_in[14]; const float* b5 = (const float*)d_in[15];
    float* out = (float*)d_out;

    // -------- workspace layout (~194 MB total) --------
    char* p = (char*)d_ws;
    int* idx = (int*)p;                 p += (size_t)M1 * 4;                 // 1.3 MB
    // arena A (84 MB): y1 bf16 [M1,64] @0, y2 bf16 [M1,64] @42MB; later y5 fp32 [M5,1024] @0
    bf16_t* y1 = (bf16_t*)p;
    float*  y5 = (float*)p;             p += (size_t)M1 * 64 * 2;
    bf16_t* y2 = (bf16_t*)p;            p += (size_t)M1 * 64 * 2;
    bf16_t* y3 = (bf16_t*)p;            p += (size_t)M1 * 128 * 2;          // 84 MB
    float* c1 = (float*)p;              p += (size_t)M5 * 64 * 4;           // cat slabs
    float* c2 = (float*)p;              p += (size_t)M5 * 64 * 4;
    float* c3 = (float*)p;              p += (size_t)M5 * 128 * 4;
    float* c4 = (float*)p;              p += (size_t)M5 * 256 * 4;
    float* st1 = (float*)p;             p += 64 * 2 * 64 * 4;
    float* st2 = (float*)p;             p += 64 * 2 * 64 * 4;
    float* st3 = (float*)p;             p += 64 * 2 * 128 * 4;
    float* st4 = (float*)p;             p += 64 * 2 * 256 * 4;
    float* st5 = (float*)p;             p += 64 * 2 * 1024 * 4;
    float* s1 = (float*)p; p += 64 * 4;   float* t1 = (float*)p; p += 64 * 4;
    float* s2 = (float*)p; p += 64 * 4;   float* t2 = (float*)p; p += 64 * 4;
    float* s3 = (float*)p; p += 128 * 4;  float* t3 = (float*)p; p += 128 * 4;
    float* s4 = (float*)p; p += 256 * 4;  float* t4 = (float*)p; p += 256 * 4;
    float* s5 = (float*)p; p += 1024 * 4; float* t5 = (float*)p; p += 1024 * 4;

    // zero bucketed stats (ws is poisoned 0xAA before every timed launch)
    size_t statsBytes = (size_t)(64 * 2 * (64 + 64 + 128 + 256 + 1024)) * 4;
    hipMemsetAsync(st1, 0, statsBytes, stream);

    const float invM14 = 1.0f / (float)M1;
    const float invM5  = 1.0f / (float)M5;

    knn_kernel<<<64, 256, 0, stream>>>(x, idx);

    // stage 1
    conv1_kernel<<<M1 / 64, 256, 0, stream>>>(x, idx, W1, y1, st1);
    finalize_kernel<<<1, 256, 0, stream>>>(st1, g1, b1, s1, t1, 64, invM14);
    maxk_kernel<<<(M5 * 64) / 256, 256, 0, stream>>>(y1, s1, t1, c1, 64, 6);

    // stage 2
    gemm_bn_bf16<<<dim3(M1 / 64, 1), 256, 0, stream>>>(y1, W2, s1, t1, y2, st2, M1, 64, 64);
    finalize_kernel<<<1, 256, 0, stream>>>(st2, g2, b2, s2, t2, 64, invM14);
    maxk_kernel<<<(M5 * 64) / 256, 256, 0, stream>>>(y2, s2, t2, c2, 64, 6);

    // stage 3
    gemm_bn_bf16<<<dim3(M1 / 64, 2), 256, 0, stream>>>(y2, W3, s2, t2, y3, st3, M1, 64, 128);
    finalize_kernel<<<1, 256, 0, stream>>>(st3, g3, b3, s3, t3, 128, invM14);
    maxk_kernel<<<(M5 * 128) / 256, 256, 0, stream>>>(y3, s3, t3, c3, 128, 7);

    // stage 4: pass 1 = stats only (y4 never materialized), pass 2 = fused BN+max
    gemm_bn_bf16<<<dim3(M1 / 64, 4), 256, 0, stream>>>(y3, W4, s3, t3, (bf16_t*)nullptr, st4, M1, 128, 256);
    finalize_kernel<<<1, 256, 0, stream>>>(st4, g4, b4, s4, t4, 256, invM14);
    gemm4_fused<<<dim3(M1 / 80, 4), 256, 0, stream>>>(y3, W4, s3, t3, s4, t4, c4);

    // stage 5
    gemm5_kernel<<<dim3(M5 / 64, 16), 256, 0, stream>>>(c1, c2, c3, c4, W5, y5, st5);
    finalize_kernel<<<4, 256, 0, stream>>>(st5, g5, b5, s5, t5, 1024, invM5);

    out_kernel<<<dim3(NPTS / 64, 1024 / 32, BATCH), 256, 0, stream>>>(y5, s5, t5, out);
}

// Round 4
// 1394.029 us; speedup vs baseline: 2.5388x; 2.5388x over previous
//
#include <hip/hip_runtime.h>

#define BATCH 8
#define NPTS  2048
#define KNN   20
#define M1    (BATCH * NPTS * KNN)   // 327680 rows for conv stages
#define M5    (BATCH * NPTS)         // 16384 rows for final projection
#define EPSBN 1e-5f

typedef unsigned short bf16_t;

__device__ __forceinline__ float bf2f(bf16_t u) {
    return __uint_as_float(((unsigned int)u) << 16);
}
__device__ __forceinline__ bf16_t f2bf(float f) {
    unsigned int u = __float_as_uint(f);
    return (bf16_t)((u + 0x7fffu + ((u >> 16) & 1u)) >> 16);
}
__device__ __forceinline__ float lrelu(float v) { return v >= 0.f ? v : 0.2f * v; }

// ---------------------------------------------------------------------------
// KNN v2 — one wave per point; exact same fp32 arithmetic as numpy reference:
//   inner = (x0n*x0m + x1n*x1m) + x2n*x2m   ; xx = (x0^2+x1^2)+x2^2
//   pdist = (2*inner - xx_n) - xx_m          (all __f*_rn, no FMA)
// Keys: order-preserving sortable u32 of pdist, packed u64 with (2047-m) in
// low 11 bits -> max = largest dist, tie -> lower index (lax.top_k stable).
// Each lane owns 32 strided candidates, keeps top-2 in registers; 20 rounds
// of wave-wide 64-bit max extraction; owner promotes backup or (rarely)
// rescans its 32 LDS slots (extracted slots marked 0 < any real key).
// No dynamically-indexed private arrays -> no scratch traffic.
// ---------------------------------------------------------------------------
__global__ __launch_bounds__(256) void knn_kernel(const float* __restrict__ x,
                                                  int* __restrict__ idx)
{
    __shared__ float xs0[NPTS], xs1[NPTS], xs2[NPTS], xxs[NPTS];
    __shared__ unsigned int keys[4][NPTS];
    int t = threadIdx.x;
    int b = blockIdx.x >> 9;              // 512 blocks per batch
    int base = (blockIdx.x & 511) * 4;    // 4 points per block (one per wave)
    const float* xb = x + (size_t)b * 3 * NPTS;
    for (int i = t; i < NPTS; i += 256) {
        float a0 = xb[i], a1 = xb[NPTS + i], a2 = xb[2 * NPTS + i];
        xs0[i] = a0; xs1[i] = a1; xs2[i] = a2;
        xxs[i] = __fadd_rn(__fadd_rn(__fmul_rn(a0, a0), __fmul_rn(a1, a1)),
                           __fmul_rn(a2, a2));
    }
    __syncthreads();
    int w = t >> 6, lane = t & 63;
    int n = base + w;
    float xn0 = xs0[n], xn1 = xs1[n], xn2 = xs2[n], xxn = xxs[n];
    unsigned long long k1 = 0ULL, k2 = 0ULL;   // 0 < any real packed key
#pragma unroll 4
    for (int j = 0; j < NPTS / 64; ++j) {
        int m = j * 64 + lane;
        float inner = __fadd_rn(__fadd_rn(__fmul_rn(xn0, xs0[m]),
                                          __fmul_rn(xn1, xs1[m])),
                                __fmul_rn(xn2, xs2[m]));
        float d = __fsub_rn(__fsub_rn(__fmul_rn(2.0f, inner), xxn), xxs[m]);
        unsigned int u = __float_as_uint(d);
        unsigned int s = u ^ ((u >> 31) ? 0xFFFFFFFFu : 0x80000000u);
        keys[w][m] = s;
        unsigned long long kp = ((unsigned long long)s << 11)
                              | (unsigned int)(NPTS - 1 - m);
        if (kp > k1)      { k2 = k1; k1 = kp; }
        else if (kp > k2) { k2 = kp; }
    }
    int* op = idx + (size_t)(b * NPTS + n) * KNN;
    for (int r = 0; r < KNN; ++r) {
        unsigned long long km = k1;
#pragma unroll
        for (int off = 32; off > 0; off >>= 1) {
            unsigned long long o = __shfl_xor(km, off);
            km = o > km ? o : km;
        }
        int m_ex = NPTS - 1 - (int)(km & 0x7FFULL);
        if (lane == 0) op[r] = m_ex;
        if ((m_ex & 63) == lane) {          // this lane owned the extracted key
            keys[w][m_ex] = 0u;
            if (k2 != 0ULL) { k1 = k2; k2 = 0ULL; }
            else {                           // rare: rebuild top-2 of survivors
                k1 = 0ULL; k2 = 0ULL;
                for (int j = 0; j < NPTS / 64; ++j) {
                    int m = j * 64 + lane;
                    unsigned int s = keys[w][m];
                    if (s) {
                        unsigned long long kp = ((unsigned long long)s << 11)
                                              | (unsigned int)(NPTS - 1 - m);
                        if (kp > k1)      { k2 = k1; k1 = kp; }
                        else if (kp > k2) { k2 = kp; }
                    }
                }
            }
        }
    }
}

// ---------------------------------------------------------------------------
// conv1: gather edge features [xj-xi, xi] (6ch), multiply by W1 [64,6].
// Writes y1 [M1,64] bf16 + bucketed (sum,sumsq) stats via atomics.
// ---------------------------------------------------------------------------
__global__ __launch_bounds__(256) void conv1_kernel(const float* __restrict__ x,
                                                    const int* __restrict__ idx,
                                                    const float* __restrict__ W1,
                                                    bf16_t* __restrict__ Y,
                                                    float* __restrict__ st)
{
    __shared__ float f[64][6];
    __shared__ float w[384];
    __shared__ float red[256];
    int t = threadIdx.x;
    for (int i = t; i < 384; i += 256) w[i] = W1[i];
    int row0 = blockIdx.x * 64;
    if (t < 64) {
        int gr = row0 + t;
        int bn = gr / KNN;
        int j = idx[gr];
        int b = bn >> 11, n = bn & (NPTS - 1);
        const float* xb = x + (size_t)b * 3 * NPTS;
        float xi0 = xb[n], xi1 = xb[NPTS + n], xi2 = xb[2 * NPTS + n];
        float xj0 = xb[j], xj1 = xb[NPTS + j], xj2 = xb[2 * NPTS + j];
        f[t][0] = xj0 - xi0; f[t][1] = xj1 - xi1; f[t][2] = xj2 - xi2;
        f[t][3] = xi0;       f[t][4] = xi1;       f[t][5] = xi2;
    }
    __syncthreads();
    int tx = t & 63, ty = t >> 6;
    float wc0 = w[tx * 6 + 0], wc1 = w[tx * 6 + 1], wc2 = w[tx * 6 + 2];
    float wc3 = w[tx * 6 + 3], wc4 = w[tx * 6 + 4], wc5 = w[tx * 6 + 5];
    float ssum = 0.f, ssq = 0.f;
#pragma unroll
    for (int i = 0; i < 16; ++i) {
        int r = ty * 16 + i;
        float yv = f[r][0] * wc0 + f[r][1] * wc1 + f[r][2] * wc2 +
                   f[r][3] * wc3 + f[r][4] * wc4 + f[r][5] * wc5;
        Y[(size_t)(row0 + r) * 64 + tx] = f2bf(yv);
        ssum += yv; ssq += yv * yv;
    }
    int bucket = blockIdx.x & 63;
    red[ty * 64 + tx] = ssum;
    __syncthreads();
    if (t < 64) {
        float v = red[t] + red[64 + t] + red[128 + t] + red[192 + t];
        atomicAdd(&st[bucket * 128 + t], v);
    }
    __syncthreads();
    red[ty * 64 + tx] = ssq;
    __syncthreads();
    if (t < 64) {
        float v = red[t] + red[64 + t] + red[128 + t] + red[192 + t];
        atomicAdd(&st[bucket * 128 + 64 + t], v);
    }
}

// ---------------------------------------------------------------------------
// Generic fused GEMM on bf16 A: Y[M,Nout](bf16) = act(A)[M,K] * W[Nout,K]^T
//   act(a) = leaky_relu(a*sIn[k]+tIn[k]) if sIn, else identity.
// Y==nullptr -> stats-only pass. Stats: 64-bucket (sum,sumsq) atomics.
// 64x64 tile, 256 threads, 4x4 micro-tile, K-chunk 16.
// ---------------------------------------------------------------------------
__global__ __launch_bounds__(256) void gemm_bn_bf16(const bf16_t* __restrict__ A,
                                                    const float* __restrict__ W,
                                                    const float* __restrict__ sIn,
                                                    const float* __restrict__ tIn,
                                                    bf16_t* __restrict__ Y,
                                                    float* __restrict__ st,
                                                    int M, int K, int Nout)
{
    __shared__ float As[16][64];
    __shared__ float Bs[16][64];
    int t = threadIdx.x;
    int tx = t & 15, ty = t >> 4;
    size_t row0 = (size_t)blockIdx.x * 64;
    int col0 = blockIdx.y * 64;
    int lm = t >> 2, lk = (t & 3) * 4;
    float acc[4][4] = {};
    const bf16_t* Ap = A + (row0 + lm) * K + lk;
    const float* Wp = W + (size_t)(col0 + lm) * K + lk;
    for (int k0 = 0; k0 < K; k0 += 16) {
        ushort4 au = *(const ushort4*)(Ap + k0);
        float4 av = make_float4(bf2f(au.x), bf2f(au.y), bf2f(au.z), bf2f(au.w));
        if (sIn) {
            float4 sv = *(const float4*)(sIn + k0 + lk);
            float4 tv = *(const float4*)(tIn + k0 + lk);
            av.x = lrelu(fmaf(av.x, sv.x, tv.x));
            av.y = lrelu(fmaf(av.y, sv.y, tv.y));
            av.z = lrelu(fmaf(av.z, sv.z, tv.z));
            av.w = lrelu(fmaf(av.w, sv.w, tv.w));
        }
        As[lk + 0][lm] = av.x; As[lk + 1][lm] = av.y;
        As[lk + 2][lm] = av.z; As[lk + 3][lm] = av.w;
        float4 bv = *(const float4*)(Wp + k0);
        Bs[lk + 0][lm] = bv.x; Bs[lk + 1][lm] = bv.y;
        Bs[lk + 2][lm] = bv.z; Bs[lk + 3][lm] = bv.w;
        __syncthreads();
#pragma unroll
        for (int kk = 0; kk < 16; ++kk) {
            float4 a4 = *(const float4*)&As[kk][ty * 4];
            float4 b4 = *(const float4*)&Bs[kk][tx * 4];
            float a[4] = { a4.x, a4.y, a4.z, a4.w };
            float bb[4] = { b4.x, b4.y, b4.z, b4.w };
#pragma unroll
            for (int i = 0; i < 4; ++i)
#pragma unroll
                for (int j = 0; j < 4; ++j)
                    acc[i][j] = fmaf(a[i], bb[j], acc[i][j]);
        }
        __syncthreads();
    }
    if (Y) {
#pragma unroll
        for (int i = 0; i < 4; ++i) {
            ushort4 o;
            o.x = f2bf(acc[i][0]); o.y = f2bf(acc[i][1]);
            o.z = f2bf(acc[i][2]); o.w = f2bf(acc[i][3]);
            *(ushort4*)&Y[(row0 + ty * 4 + i) * Nout + col0 + tx * 4] = o;
        }
    }
    __syncthreads();
    float* red = &As[0][0];
    int bucket = blockIdx.x & 63;
    float p0[4], p1[4];
#pragma unroll
    for (int j = 0; j < 4; ++j) {
        p0[j] = acc[0][j] + acc[1][j] + acc[2][j] + acc[3][j];
        p1[j] = acc[0][j] * acc[0][j] + acc[1][j] * acc[1][j] +
                acc[2][j] * acc[2][j] + acc[3][j] * acc[3][j];
    }
#pragma unroll
    for (int j = 0; j < 4; ++j) red[ty * 64 + tx * 4 + j] = p0[j];
    __syncthreads();
    if (t < 64) {
        float v = 0.f;
#pragma unroll
        for (int r = 0; r < 16; ++r) v += red[r * 64 + t];
        atomicAdd(&st[(size_t)bucket * 2 * Nout + col0 + t], v);
    }
    __syncthreads();
#pragma unroll
    for (int j = 0; j < 4; ++j) red[ty * 64 + tx * 4 + j] = p1[j];
    __syncthreads();
    if (t < 64) {
        float v = 0.f;
#pragma unroll
        for (int r = 0; r < 16; ++r) v += red[r * 64 + t];
        atomicAdd(&st[(size_t)bucket * 2 * Nout + Nout + col0 + t], v);
    }
}

// ---------------------------------------------------------------------------
// Stage-4 fused pass 2: y4 never materialized. 80-row tile = exactly 4 points
// (4*20 edges). Computes y4 tile, applies BN+LReLU (s4,t4 known from pass 1),
// max-over-k in LDS, writes cat slab4 [M5,256] directly.
// ---------------------------------------------------------------------------
__global__ __launch_bounds__(256) void gemm4_fused(const bf16_t* __restrict__ A,
                                                   const float* __restrict__ W,
                                                   const float* __restrict__ s3,
                                                   const float* __restrict__ t3,
                                                   const float* __restrict__ s4,
                                                   const float* __restrict__ t4,
                                                   float* __restrict__ slab4)
{
    const int K = 128;
    __shared__ float As[16][80];
    __shared__ float Bs[16][64];
    __shared__ float tile[80][65];
    int t = threadIdx.x;
    int row0 = blockIdx.x * 80;       // 4096 blocks: 4 points each
    int col0 = blockIdx.y * 64;       // 4 col tiles
    int tx = t & 15, ty = t >> 4;     // cols tx*4.., rows ty*5..
    float acc[5][4] = {};
    int lmB = t >> 2, lkB = (t & 3) * 4;
    const float* Wp = W + (size_t)(col0 + lmB) * K + lkB;
    for (int k0 = 0; k0 < K; k0 += 16) {
        for (int i = t; i < 320; i += 256) {
            int r = i >> 2, kq = (i & 3) * 4;
            int kc = k0 + kq;
            ushort4 au = *(const ushort4*)(A + (size_t)(row0 + r) * K + kc);
            float4 sv = *(const float4*)(s3 + kc);
            float4 tv = *(const float4*)(t3 + kc);
            As[kq + 0][r] = lrelu(fmaf(bf2f(au.x), sv.x, tv.x));
            As[kq + 1][r] = lrelu(fmaf(bf2f(au.y), sv.y, tv.y));
            As[kq + 2][r] = lrelu(fmaf(bf2f(au.z), sv.z, tv.z));
            As[kq + 3][r] = lrelu(fmaf(bf2f(au.w), sv.w, tv.w));
        }
        float4 bv = *(const float4*)(Wp + k0);
        Bs[lkB + 0][lmB] = bv.x; Bs[lkB + 1][lmB] = bv.y;
        Bs[lkB + 2][lmB] = bv.z; Bs[lkB + 3][lmB] = bv.w;
        __syncthreads();
#pragma unroll
        for (int kk = 0; kk < 16; ++kk) {
            float4 b4 = *(const float4*)&Bs[kk][tx * 4];
            float ar[5];
#pragma unroll
            for (int i = 0; i < 5; ++i) ar[i] = As[kk][ty * 5 + i];
            float bb[4] = { b4.x, b4.y, b4.z, b4.w };
#pragma unroll
            for (int i = 0; i < 5; ++i)
#pragma unroll
                for (int j = 0; j < 4; ++j)
                    acc[i][j] = fmaf(ar[i], bb[j], acc[i][j]);
        }
        __syncthreads();
    }
    float s4c[4], t4c[4];
#pragma unroll
    for (int j = 0; j < 4; ++j) {
        s4c[j] = s4[col0 + tx * 4 + j];
        t4c[j] = t4[col0 + tx * 4 + j];
    }
#pragma unroll
    for (int i = 0; i < 5; ++i)
#pragma unroll
        for (int j = 0; j < 4; ++j)
            tile[ty * 5 + i][tx * 4 + j] = lrelu(fmaf(acc[i][j], s4c[j], t4c[j]));
    __syncthreads();
    int pt = t >> 6, col = t & 63;
    float m = -1e30f;
#pragma unroll
    for (int k = 0; k < KNN; ++k) m = fmaxf(m, tile[pt * KNN + k][col]);
    int point = blockIdx.x * 4 + pt;
    slab4[(size_t)point * 256 + col0 + col] = m;
}

// ---------------------------------------------------------------------------
// Final GEMM: y5[M5,1024] = cat[M5,512] * W5^T, cat gathered from 4 slabs.
// ---------------------------------------------------------------------------
__global__ __launch_bounds__(256) void gemm5_kernel(const float* __restrict__ c1,
                                                    const float* __restrict__ c2,
                                                    const float* __restrict__ c3,
                                                    const float* __restrict__ c4,
                                                    const float* __restrict__ W,
                                                    float* __restrict__ Y,
                                                    float* __restrict__ st)
{
    const int K = 512, Nout = 1024;
    __shared__ float As[16][64];
    __shared__ float Bs[16][64];
    int t = threadIdx.x;
    int tx = t & 15, ty = t >> 4;
    size_t row0 = (size_t)blockIdx.x * 64;
    int col0 = blockIdx.y * 64;
    int lm = t >> 2, lk = (t & 3) * 4;
    float acc[4][4] = {};
    size_t row = row0 + lm;
    const float* Wp = W + (size_t)(col0 + lm) * K + lk;
    for (int k0 = 0; k0 < K; k0 += 16) {
        int kk0 = k0 + lk;
        const float* sp;
        if (kk0 < 64)       sp = c1 + row * 64  + kk0;
        else if (kk0 < 128) sp = c2 + row * 64  + (kk0 - 64);
        else if (kk0 < 256) sp = c3 + row * 128 + (kk0 - 128);
        else                sp = c4 + row * 256 + (kk0 - 256);
        float4 av = *(const float4*)sp;
        As[lk + 0][lm] = av.x; As[lk + 1][lm] = av.y;
        As[lk + 2][lm] = av.z; As[lk + 3][lm] = av.w;
        float4 bv = *(const float4*)(Wp + k0);
        Bs[lk + 0][lm] = bv.x; Bs[lk + 1][lm] = bv.y;
        Bs[lk + 2][lm] = bv.z; Bs[lk + 3][lm] = bv.w;
        __syncthreads();
#pragma unroll
        for (int kk = 0; kk < 16; ++kk) {
            float4 a4 = *(const float4*)&As[kk][ty * 4];
            float4 b4 = *(const float4*)&Bs[kk][tx * 4];
            float a[4] = { a4.x, a4.y, a4.z, a4.w };
            float bb[4] = { b4.x, b4.y, b4.z, b4.w };
#pragma unroll
            for (int i = 0; i < 4; ++i)
#pragma unroll
                for (int j = 0; j < 4; ++j)
                    acc[i][j] = fmaf(a[i], bb[j], acc[i][j]);
        }
        __syncthreads();
    }
#pragma unroll
    for (int i = 0; i < 4; ++i) {
        float4 v = make_float4(acc[i][0], acc[i][1], acc[i][2], acc[i][3]);
        *(float4*)&Y[(row0 + ty * 4 + i) * Nout + col0 + tx * 4] = v;
    }
    __syncthreads();
    float* red = &As[0][0];
    int bucket = blockIdx.x & 63;
    float p0[4], p1[4];
#pragma unroll
    for (int j = 0; j < 4; ++j) {
        p0[j] = acc[0][j] + acc[1][j] + acc[2][j] + acc[3][j];
        p1[j] = acc[0][j] * acc[0][j] + acc[1][j] * acc[1][j] +
                acc[2][j] * acc[2][j] + acc[3][j] * acc[3][j];
    }
#pragma unroll
    for (int j = 0; j < 4; ++j) red[ty * 64 + tx * 4 + j] = p0[j];
    __syncthreads();
    if (t < 64) {
        float v = 0.f;
#pragma unroll
        for (int r = 0; r < 16; ++r) v += red[r * 64 + t];
        atomicAdd(&st[(size_t)bucket * 2 * Nout + col0 + t], v);
    }
    __syncthreads();
#pragma unroll
    for (int j = 0; j < 4; ++j) red[ty * 64 + tx * 4 + j] = p1[j];
    __syncthreads();
    if (t < 64) {
        float v = 0.f;
#pragma unroll
        for (int r = 0; r < 16; ++r) v += red[r * 64 + t];
        atomicAdd(&st[(size_t)bucket * 2 * Nout + Nout + col0 + t], v);
    }
}

// ---------------------------------------------------------------------------
__global__ void finalize_kernel(const float* __restrict__ st,
                                const float* __restrict__ g,
                                const float* __restrict__ bb,
                                float* __restrict__ s, float* __restrict__ tt,
                                int C, float invM)
{
    int c = blockIdx.x * blockDim.x + threadIdx.x;
    if (c >= C) return;
    float sum = 0.f, sq = 0.f;
    for (int bk = 0; bk < 64; ++bk) {
        sum += st[(size_t)bk * 2 * C + c];
        sq  += st[(size_t)bk * 2 * C + C + c];
    }
    float mu  = sum * invM;
    float var = sq * invM - mu * mu;
    float sc  = g[c] * rsqrtf(var + EPSBN);
    s[c]  = sc;
    tt[c] = bb[c] - mu * sc;
}

// ---------------------------------------------------------------------------
// Max over k of leaky_relu(y*s+t) -> one cat slab [M5, C].
// ---------------------------------------------------------------------------
__global__ __launch_bounds__(256) void maxk_kernel(const bf16_t* __restrict__ Y,
                                                   const float* __restrict__ s,
                                                   const float* __restrict__ tt,
                                                   float* __restrict__ slab,
                                                   int C, int logC)
{
    int gid = blockIdx.x * 256 + threadIdx.x;
    int c = gid & (C - 1);
    int bn = gid >> logC;
    float sc = s[c], tc = tt[c];
    const bf16_t* p = Y + (size_t)bn * KNN * C + c;
    float m = -1e30f;
#pragma unroll
    for (int kk = 0; kk < KNN; ++kk) {
        float v = fmaf(bf2f(p[(size_t)kk * C]), sc, tc);
        m = fmaxf(m, lrelu(v));
    }
    slab[(size_t)bn * C + c] = m;
}

// ---------------------------------------------------------------------------
// Output: BN+LeakyReLU on y5 [B*N,1024], transposed write -> out [B,1024,N].
// ---------------------------------------------------------------------------
__global__ __launch_bounds__(256) void out_kernel(const float* __restrict__ y5,
                                                  const float* __restrict__ s,
                                                  const float* __restrict__ tt,
                                                  float* __restrict__ out)
{
    __shared__ float tile[32][65];
    int t = threadIdx.x;
    int b = blockIdx.z;
    int o0 = blockIdx.y * 32;
    int n0 = blockIdx.x * 64;
#pragma unroll
    for (int p = 0; p < 8; ++p) {
        int ol = t & 31, nl = (t >> 5) + 8 * p;
        tile[ol][nl] = y5[((size_t)b * NPTS + n0 + nl) * 1024 + o0 + ol];
    }
    __syncthreads();
#pragma unroll
    for (int p = 0; p < 8; ++p) {
        int nl = t & 63, ol = (t >> 6) + 4 * p;
        float v = fmaf(tile[ol][nl], s[o0 + ol], tt[o0 + ol]);
        out[(size_t)b * 1024 * NPTS + (size_t)(o0 + ol) * NPTS + n0 + nl] = lrelu(v);
    }
}

// ---------------------------------------------------------------------------
extern "C" void kernel_launch(void* const* d_in, const int* in_sizes, int n_in,
                              void* d_out, int out_size, void* d_ws, size_t ws_size,
                              hipStream_t stream)
{
    const float* x  = (const float*)d_in[0];
    const float* W1 = (const float*)d_in[1];
    const float* g1 = (const float*)d_in[2];  const float* b1 = (const float*)d_in[3];
    const float* W2 = (const float*)d_in[4];
    const float* g2 = (const float*)d_in[5];  const float* b2 = (const float*)d_in[6];
    const float* W3 = (const float*)d_in[7];
    const float* g3 = (const float*)d_in[8];  const float* b3 = (const float*)d_in[9];
    const float* W4 = (const float*)d_in[10];
    const float* g4 = (const float*)d_in[11]; const float* b4 = (const float*)d_in[12];
    const float* W5 = (const float*)d_in[13];
    const float* g5 = (const float*)d_in[14]; const float* b5 = (const float*)d_in[15];
    float* out = (float*)d_out;

    // -------- workspace layout (~194 MB total) --------
    char* p = (char*)d_ws;
    int* idx = (int*)p;                 p += (size_t)M1 * 4;                 // 1.3 MB
    // arena A (84 MB): y1 bf16 [M1,64] @0, y2 bf16 [M1,64] @42MB; later y5 fp32 [M5,1024] @0
    bf16_t* y1 = (bf16_t*)p;
    float*  y5 = (float*)p;             p += (size_t)M1 * 64 * 2;
    bf16_t* y2 = (bf16_t*)p;            p += (size_t)M1 * 64 * 2;
    bf16_t* y3 = (bf16_t*)p;            p += (size_t)M1 * 128 * 2;          // 84 MB
    float* c1 = (float*)p;              p += (size_t)M5 * 64 * 4;           // cat slabs
    float* c2 = (float*)p;              p += (size_t)M5 * 64 * 4;
    float* c3 = (float*)p;              p += (size_t)M5 * 128 * 4;
    float* c4 = (float*)p;              p += (size_t)M5 * 256 * 4;
    float* st1 = (float*)p;             p += 64 * 2 * 64 * 4;
    float* st2 = (float*)p;             p += 64 * 2 * 64 * 4;
    float* st3 = (float*)p;             p += 64 * 2 * 128 * 4;
    float* st4 = (float*)p;             p += 64 * 2 * 256 * 4;
    float* st5 = (float*)p;             p += 64 * 2 * 1024 * 4;
    float* s1 = (float*)p; p += 64 * 4;   float* t1 = (float*)p; p += 64 * 4;
    float* s2 = (float*)p; p += 64 * 4;   float* t2 = (float*)p; p += 64 * 4;
    float* s3 = (float*)p; p += 128 * 4;  float* t3 = (float*)p; p += 128 * 4;
    float* s4 = (float*)p; p += 256 * 4;  float* t4 = (float*)p; p += 256 * 4;
    float* s5 = (float*)p; p += 1024 * 4; float* t5 = (float*)p; p += 1024 * 4;

    // zero bucketed stats (ws is poisoned 0xAA before every timed launch)
    size_t statsBytes = (size_t)(64 * 2 * (64 + 64 + 128 + 256 + 1024)) * 4;
    hipMemsetAsync(st1, 0, statsBytes, stream);

    const float invM14 = 1.0f / (float)M1;
    const float invM5  = 1.0f / (float)M5;

    knn_kernel<<<M5 / 4, 256, 0, stream>>>(x, idx);

    // stage 1
    conv1_kernel<<<M1 / 64, 256, 0, stream>>>(x, idx, W1, y1, st1);
    finalize_kernel<<<1, 256, 0, stream>>>(st1, g1, b1, s1, t1, 64, invM14);
    maxk_kernel<<<(M5 * 64) / 256, 256, 0, stream>>>(y1, s1, t1, c1, 64, 6);

    // stage 2
    gemm_bn_bf16<<<dim3(M1 / 64, 1), 256, 0, stream>>>(y1, W2, s1, t1, y2, st2, M1, 64, 64);
    finalize_kernel<<<1, 256, 0, stream>>>(st2, g2, b2, s2, t2, 64, invM14);
    maxk_kernel<<<(M5 * 64) / 256, 256, 0, stream>>>(y2, s2, t2, c2, 64, 6);

    // stage 3
    gemm_bn_bf16<<<dim3(M1 / 64, 2), 256, 0, stream>>>(y2, W3, s2, t2, y3, st3, M1, 64, 128);
    finalize_kernel<<<1, 256, 0, stream>>>(st3, g3, b3, s3, t3, 128, invM14);
    maxk_kernel<<<(M5 * 128) / 256, 256, 0, stream>>>(y3, s3, t3, c3, 128, 7);

    // stage 4: pass 1 = stats only (y4 never materialized), pass 2 = fused BN+max
    gemm_bn_bf16<<<dim3(M1 / 64, 4), 256, 0, stream>>>(y3, W4, s3, t3, (bf16_t*)nullptr, st4, M1, 128, 256);
    finalize_kernel<<<1, 256, 0, stream>>>(st4, g4, b4, s4, t4, 256, invM14);
    gemm4_fused<<<dim3(M1 / 80, 4), 256, 0, stream>>>(y3, W4, s3, t3, s4, t4, c4);

    // stage 5
    gemm5_kernel<<<dim3(M5 / 64, 16), 256, 0, stream>>>(c1, c2, c3, c4, W5, y5, st5);
    finalize_kernel<<<4, 256, 0, stream>>>(st5, g5, b5, s5, t5, 1024, invM5);

    out_kernel<<<dim3(NPTS / 64, 1024 / 32, BATCH), 256, 0, stream>>>(y5, s5, t5, out);
}

// Round 5
// 650.314 us; speedup vs baseline: 5.4423x; 2.1436x over previous
//
#include <hip/hip_runtime.h>

#define BATCH 8
#define NPTS  2048
#define KNN   20
#define M1    (BATCH * NPTS * KNN)   // 327680 rows for conv stages
#define M5    (BATCH * NPTS)         // 16384 rows for final projection
#define EPSBN 1e-5f
#define LDA   40                      // padded LDS k-stride (halfs): 2-way max aliasing

typedef unsigned short bf16_t;
typedef _Float16 half8 __attribute__((ext_vector_type(8)));
typedef _Float16 half4v __attribute__((ext_vector_type(4)));
typedef float    floatx4 __attribute__((ext_vector_type(4)));

__device__ __forceinline__ float bf2f(bf16_t u) {
    return __uint_as_float(((unsigned int)u) << 16);
}
__device__ __forceinline__ bf16_t f2bf(float f) {
    unsigned int u = __float_as_uint(f);
    return (bf16_t)((u + 0x7fffu + ((u >> 16) & 1u)) >> 16);
}
__device__ __forceinline__ float lrelu(float v) { return v >= 0.f ? v : 0.2f * v; }

// ---------------------------------------------------------------------------
// KNN — exact fp32 reference arithmetic, one wave per point (round-4 verified)
// ---------------------------------------------------------------------------
__global__ __launch_bounds__(256) void knn_kernel(const float* __restrict__ x,
                                                  int* __restrict__ idx)
{
    __shared__ float xs0[NPTS], xs1[NPTS], xs2[NPTS], xxs[NPTS];
    __shared__ unsigned int keys[4][NPTS];
    int t = threadIdx.x;
    int b = blockIdx.x >> 9;
    int base = (blockIdx.x & 511) * 4;
    const float* xb = x + (size_t)b * 3 * NPTS;
    for (int i = t; i < NPTS; i += 256) {
        float a0 = xb[i], a1 = xb[NPTS + i], a2 = xb[2 * NPTS + i];
        xs0[i] = a0; xs1[i] = a1; xs2[i] = a2;
        xxs[i] = __fadd_rn(__fadd_rn(__fmul_rn(a0, a0), __fmul_rn(a1, a1)),
                           __fmul_rn(a2, a2));
    }
    __syncthreads();
    int w = t >> 6, lane = t & 63;
    int n = base + w;
    float xn0 = xs0[n], xn1 = xs1[n], xn2 = xs2[n], xxn = xxs[n];
    unsigned long long k1 = 0ULL, k2 = 0ULL;
#pragma unroll 4
    for (int j = 0; j < NPTS / 64; ++j) {
        int m = j * 64 + lane;
        float inner = __fadd_rn(__fadd_rn(__fmul_rn(xn0, xs0[m]),
                                          __fmul_rn(xn1, xs1[m])),
                                __fmul_rn(xn2, xs2[m]));
        float d = __fsub_rn(__fsub_rn(__fmul_rn(2.0f, inner), xxn), xxs[m]);
        unsigned int u = __float_as_uint(d);
        unsigned int s = u ^ ((u >> 31) ? 0xFFFFFFFFu : 0x80000000u);
        keys[w][m] = s;
        unsigned long long kp = ((unsigned long long)s << 11)
                              | (unsigned int)(NPTS - 1 - m);
        if (kp > k1)      { k2 = k1; k1 = kp; }
        else if (kp > k2) { k2 = kp; }
    }
    int* op = idx + (size_t)(b * NPTS + n) * KNN;
    for (int r = 0; r < KNN; ++r) {
        unsigned long long km = k1;
#pragma unroll
        for (int off = 32; off > 0; off >>= 1) {
            unsigned long long o = __shfl_xor(km, off);
            km = o > km ? o : km;
        }
        int m_ex = NPTS - 1 - (int)(km & 0x7FFULL);
        if (lane == 0) op[r] = m_ex;
        if ((m_ex & 63) == lane) {
            keys[w][m_ex] = 0u;
            if (k2 != 0ULL) { k1 = k2; k2 = 0ULL; }
            else {
                k1 = 0ULL; k2 = 0ULL;
                for (int j = 0; j < NPTS / 64; ++j) {
                    int m = j * 64 + lane;
                    unsigned int s = keys[w][m];
                    if (s) {
                        unsigned long long kp = ((unsigned long long)s << 11)
                                              | (unsigned int)(NPTS - 1 - m);
                        if (kp > k1)      { k2 = k1; k1 = kp; }
                        else if (kp > k2) { k2 = kp; }
                    }
                }
            }
        }
    }
}

// ---------------------------------------------------------------------------
// conv1 (unchanged): edge features * W1 -> y1 bf16 + stats
// ---------------------------------------------------------------------------
__global__ __launch_bounds__(256) void conv1_kernel(const float* __restrict__ x,
                                                    const int* __restrict__ idx,
                                                    const float* __restrict__ W1,
                                                    bf16_t* __restrict__ Y,
                                                    float* __restrict__ st)
{
    __shared__ float f[64][6];
    __shared__ float w[384];
    __shared__ float red[256];
    int t = threadIdx.x;
    for (int i = t; i < 384; i += 256) w[i] = W1[i];
    int row0 = blockIdx.x * 64;
    if (t < 64) {
        int gr = row0 + t;
        int bn = gr / KNN;
        int j = idx[gr];
        int b = bn >> 11, n = bn & (NPTS - 1);
        const float* xb = x + (size_t)b * 3 * NPTS;
        float xi0 = xb[n], xi1 = xb[NPTS + n], xi2 = xb[2 * NPTS + n];
        float xj0 = xb[j], xj1 = xb[NPTS + j], xj2 = xb[2 * NPTS + j];
        f[t][0] = xj0 - xi0; f[t][1] = xj1 - xi1; f[t][2] = xj2 - xi2;
        f[t][3] = xi0;       f[t][4] = xi1;       f[t][5] = xi2;
    }
    __syncthreads();
    int tx = t & 63, ty = t >> 6;
    float wc0 = w[tx * 6 + 0], wc1 = w[tx * 6 + 1], wc2 = w[tx * 6 + 2];
    float wc3 = w[tx * 6 + 3], wc4 = w[tx * 6 + 4], wc5 = w[tx * 6 + 5];
    float ssum = 0.f, ssq = 0.f;
#pragma unroll
    for (int i = 0; i < 16; ++i) {
        int r = ty * 16 + i;
        float yv = f[r][0] * wc0 + f[r][1] * wc1 + f[r][2] * wc2 +
                   f[r][3] * wc3 + f[r][4] * wc4 + f[r][5] * wc5;
        Y[(size_t)(row0 + r) * 64 + tx] = f2bf(yv);
        ssum += yv; ssq += yv * yv;
    }
    int bucket = blockIdx.x & 63;
    red[ty * 64 + tx] = ssum;
    __syncthreads();
    if (t < 64) {
        float v = red[t] + red[64 + t] + red[128 + t] + red[192 + t];
        atomicAdd(&st[bucket * 128 + t], v);
    }
    __syncthreads();
    red[ty * 64 + tx] = ssq;
    __syncthreads();
    if (t < 64) {
        float v = red[t] + red[64 + t] + red[128 + t] + red[192 + t];
        atomicAdd(&st[bucket * 128 + 64 + t], v);
    }
}

// ---------------------------------------------------------------------------
// MFMA GEMM (s2/s3/s4-stats): Y[M,Nout] = act(A)[M,K] * W[Nout,K]^T
// A bf16; act = lrelu(a*sIn+tIn) applied in staging, rounded to fp16.
// W fp32 -> fp16 in staging. 16x16x32_f16 MFMA, fp32 accumulate.
// Tile 128x64, BK=32, 256 thr (4 waves x 32 rows). Y optional (bf16).
// Stats: quad-shfl reduce -> LDS atomics -> 64-bucket global atomics.
// ---------------------------------------------------------------------------
__global__ __launch_bounds__(256) void gemm_mfma_bn(const bf16_t* __restrict__ A,
                                                    const float* __restrict__ W,
                                                    const float* __restrict__ sIn,
                                                    const float* __restrict__ tIn,
                                                    bf16_t* __restrict__ Y,
                                                    float* __restrict__ st,
                                                    int K, int Nout)
{
    __shared__ _Float16 Asm[128][LDA];
    __shared__ _Float16 Bsm[64][LDA];
    __shared__ float colsum[64], colsq[64];
    int t = threadIdx.x;
    int lane = t & 63, w = t >> 6;
    int quad = lane >> 4, l16 = lane & 15;
    size_t row0 = (size_t)blockIdx.x * 128;
    int col0 = blockIdx.y * 64;
    if (t < 64) { colsum[t] = 0.f; colsq[t] = 0.f; }
    floatx4 acc[2][4];
#pragma unroll
    for (int mt = 0; mt < 2; ++mt)
#pragma unroll
        for (int nt = 0; nt < 4; ++nt)
            acc[mt][nt] = (floatx4){0.f, 0.f, 0.f, 0.f};

    for (int k0 = 0; k0 < K; k0 += 32) {
#pragma unroll
        for (int it = 0; it < 2; ++it) {           // A: 128x32 bf16 -> act -> f16
            int i = t + it * 256;
            int r = i >> 2, ko = (i & 3) * 8;
            uint4 au = *(const uint4*)(A + (row0 + r) * K + k0 + ko);
            float4 sv0 = *(const float4*)(sIn + k0 + ko);
            float4 sv1 = *(const float4*)(sIn + k0 + ko + 4);
            float4 tv0 = *(const float4*)(tIn + k0 + ko);
            float4 tv1 = *(const float4*)(tIn + k0 + ko + 4);
            half8 hv;
            hv[0] = (_Float16)lrelu(fmaf(bf2f(au.x & 0xffff), sv0.x, tv0.x));
            hv[1] = (_Float16)lrelu(fmaf(bf2f(au.x >> 16),    sv0.y, tv0.y));
            hv[2] = (_Float16)lrelu(fmaf(bf2f(au.y & 0xffff), sv0.z, tv0.z));
            hv[3] = (_Float16)lrelu(fmaf(bf2f(au.y >> 16),    sv0.w, tv0.w));
            hv[4] = (_Float16)lrelu(fmaf(bf2f(au.z & 0xffff), sv1.x, tv1.x));
            hv[5] = (_Float16)lrelu(fmaf(bf2f(au.z >> 16),    sv1.y, tv1.y));
            hv[6] = (_Float16)lrelu(fmaf(bf2f(au.w & 0xffff), sv1.z, tv1.z));
            hv[7] = (_Float16)lrelu(fmaf(bf2f(au.w >> 16),    sv1.w, tv1.w));
            *(half8*)&Asm[r][ko] = hv;
        }
#pragma unroll
        for (int it = 0; it < 2; ++it) {           // B: 64x32 fp32 -> f16
            int i = t + it * 256;
            int n = i >> 3, seg = (i & 7) * 4;
            float4 bv = *(const float4*)(W + (size_t)(col0 + n) * K + k0 + seg);
            half4v h;
            h[0] = (_Float16)bv.x; h[1] = (_Float16)bv.y;
            h[2] = (_Float16)bv.z; h[3] = (_Float16)bv.w;
            *(half4v*)&Bsm[n][seg] = h;
        }
        __syncthreads();
        half8 af[2], bf[4];
#pragma unroll
        for (int mt = 0; mt < 2; ++mt)
            af[mt] = *(const half8*)&Asm[w * 32 + mt * 16 + l16][quad * 8];
#pragma unroll
        for (int nt = 0; nt < 4; ++nt)
            bf[nt] = *(const half8*)&Bsm[nt * 16 + l16][quad * 8];
#pragma unroll
        for (int mt = 0; mt < 2; ++mt)
#pragma unroll
            for (int nt = 0; nt < 4; ++nt)
                acc[mt][nt] = __builtin_amdgcn_mfma_f32_16x16x32_f16(
                    af[mt], bf[nt], acc[mt][nt], 0, 0, 0);
        __syncthreads();
    }
    if (Y) {
#pragma unroll
        for (int mt = 0; mt < 2; ++mt)
#pragma unroll
            for (int nt = 0; nt < 4; ++nt)
#pragma unroll
                for (int r = 0; r < 4; ++r) {
                    size_t row = row0 + w * 32 + mt * 16 + quad * 4 + r;
                    Y[row * Nout + col0 + nt * 16 + l16] = f2bf(acc[mt][nt][r]);
                }
    }
#pragma unroll
    for (int nt = 0; nt < 4; ++nt) {
        float s = 0.f, q = 0.f;
#pragma unroll
        for (int mt = 0; mt < 2; ++mt)
#pragma unroll
            for (int r = 0; r < 4; ++r) {
                float v = acc[mt][nt][r];
                s += v; q += v * v;
            }
        s += __shfl_xor(s, 16); q += __shfl_xor(q, 16);
        s += __shfl_xor(s, 32); q += __shfl_xor(q, 32);
        if (quad == 0) {
            atomicAdd(&colsum[nt * 16 + l16], s);
            atomicAdd(&colsq[nt * 16 + l16], q);
        }
    }
    __syncthreads();
    int bucket = blockIdx.x & 63;
    if (t < 64) {
        atomicAdd(&st[(size_t)bucket * 2 * Nout + col0 + t], colsum[t]);
        atomicAdd(&st[(size_t)bucket * 2 * Nout + Nout + col0 + t], colsq[t]);
    }
}

// ---------------------------------------------------------------------------
// Stage-4 fused pass 2 (MFMA): BM=320 rows = 16 points; computes y4 tile,
// BN+LReLU, max-over-k via LDS, writes slab4 [M5,256]. K=128.
// Waves own 80 rows (5 m-frags); identical staging/MFMA order to the stats
// pass -> bit-identical y4 -> self-consistent BN.
// ---------------------------------------------------------------------------
__global__ __launch_bounds__(256) void gemm4_mfma(const bf16_t* __restrict__ A,
                                                  const float* __restrict__ W,
                                                  const float* __restrict__ s3,
                                                  const float* __restrict__ t3,
                                                  const float* __restrict__ s4,
                                                  const float* __restrict__ t4,
                                                  float* __restrict__ slab4)
{
    const int K = 128;
    __shared__ _Float16 Asm[320][LDA];     // 25.6 KB
    __shared__ _Float16 Bsm[64][LDA];      //  5.1 KB
    __shared__ _Float16 tile[320][72];     // 46.1 KB
    int t = threadIdx.x;
    int lane = t & 63, w = t >> 6;
    int quad = lane >> 4, l16 = lane & 15;
    size_t row0 = (size_t)blockIdx.x * 320;
    int col0 = blockIdx.y * 64;
    floatx4 acc[5][4];
#pragma unroll
    for (int mt = 0; mt < 5; ++mt)
#pragma unroll
        for (int nt = 0; nt < 4; ++nt)
            acc[mt][nt] = (floatx4){0.f, 0.f, 0.f, 0.f};

    for (int k0 = 0; k0 < K; k0 += 32) {
#pragma unroll
        for (int it = 0; it < 5; ++it) {           // A: 320x32
            int i = t + it * 256;
            int r = i >> 2, ko = (i & 3) * 8;
            uint4 au = *(const uint4*)(A + (row0 + r) * K + k0 + ko);
            float4 sv0 = *(const float4*)(s3 + k0 + ko);
            float4 sv1 = *(const float4*)(s3 + k0 + ko + 4);
            float4 tv0 = *(const float4*)(t3 + k0 + ko);
            float4 tv1 = *(const float4*)(t3 + k0 + ko + 4);
            half8 hv;
            hv[0] = (_Float16)lrelu(fmaf(bf2f(au.x & 0xffff), sv0.x, tv0.x));
            hv[1] = (_Float16)lrelu(fmaf(bf2f(au.x >> 16),    sv0.y, tv0.y));
            hv[2] = (_Float16)lrelu(fmaf(bf2f(au.y & 0xffff), sv0.z, tv0.z));
            hv[3] = (_Float16)lrelu(fmaf(bf2f(au.y >> 16),    sv0.w, tv0.w));
            hv[4] = (_Float16)lrelu(fmaf(bf2f(au.z & 0xffff), sv1.x, tv1.x));
            hv[5] = (_Float16)lrelu(fmaf(bf2f(au.z >> 16),    sv1.y, tv1.y));
            hv[6] = (_Float16)lrelu(fmaf(bf2f(au.w & 0xffff), sv1.z, tv1.z));
            hv[7] = (_Float16)lrelu(fmaf(bf2f(au.w >> 16),    sv1.w, tv1.w));
            *(half8*)&Asm[r][ko] = hv;
        }
#pragma unroll
        for (int it = 0; it < 2; ++it) {           // B: 64x32
            int i = t + it * 256;
            int n = i >> 3, seg = (i & 7) * 4;
            float4 bv = *(const float4*)(W + (size_t)(col0 + n) * K + k0 + seg);
            half4v h;
            h[0] = (_Float16)bv.x; h[1] = (_Float16)bv.y;
            h[2] = (_Float16)bv.z; h[3] = (_Float16)bv.w;
            *(half4v*)&Bsm[n][seg] = h;
        }
        __syncthreads();
        half8 af[5], bf[4];
#pragma unroll
        for (int mt = 0; mt < 5; ++mt)
            af[mt] = *(const half8*)&Asm[w * 80 + mt * 16 + l16][quad * 8];
#pragma unroll
        for (int nt = 0; nt < 4; ++nt)
            bf[nt] = *(const half8*)&Bsm[nt * 16 + l16][quad * 8];
#pragma unroll
        for (int mt = 0; mt < 5; ++mt)
#pragma unroll
            for (int nt = 0; nt < 4; ++nt)
                acc[mt][nt] = __builtin_amdgcn_mfma_f32_16x16x32_f16(
                    af[mt], bf[nt], acc[mt][nt], 0, 0, 0);
        __syncthreads();
    }
    float s4c[4], t4c[4];
#pragma unroll
    for (int nt = 0; nt < 4; ++nt) {
        s4c[nt] = s4[col0 + nt * 16 + l16];
        t4c[nt] = t4[col0 + nt * 16 + l16];
    }
#pragma unroll
    for (int mt = 0; mt < 5; ++mt)
#pragma unroll
        for (int nt = 0; nt < 4; ++nt)
#pragma unroll
            for (int r = 0; r < 4; ++r) {
                int rl = w * 80 + mt * 16 + quad * 4 + r;
                tile[rl][nt * 16 + l16] =
                    (_Float16)lrelu(fmaf(acc[mt][nt][r], s4c[nt], t4c[nt]));
            }
    __syncthreads();
    int col = t & 63;
#pragma unroll
    for (int g = 0; g < 4; ++g) {
        int pt = (t >> 6) * 4 + g;                 // 0..15
        float m = -1e30f;
#pragma unroll
        for (int k = 0; k < KNN; ++k)
            m = fmaxf(m, (float)tile[pt * KNN + k][col]);
        slab4[((size_t)blockIdx.x * 16 + pt) * 256 + col0 + col] = m;
    }
}

// ---------------------------------------------------------------------------
// Final GEMM (MFMA): y5[M5,1024] = cat[M5,512]*W5^T; cat gathered fp32->f16.
// ---------------------------------------------------------------------------
__global__ __launch_bounds__(256) void gemm5_mfma(const float* __restrict__ c1,
                                                  const float* __restrict__ c2,
                                                  const float* __restrict__ c3,
                                                  const float* __restrict__ c4,
                                                  const float* __restrict__ W,
                                                  float* __restrict__ Y,
                                                  float* __restrict__ st)
{
    const int K = 512, Nout = 1024;
    __shared__ _Float16 Asm[128][LDA];
    __shared__ _Float16 Bsm[64][LDA];
    __shared__ float colsum[64], colsq[64];
    int t = threadIdx.x;
    int lane = t & 63, w = t >> 6;
    int quad = lane >> 4, l16 = lane & 15;
    size_t row0 = (size_t)blockIdx.x * 128;
    int col0 = blockIdx.y * 64;
    if (t < 64) { colsum[t] = 0.f; colsq[t] = 0.f; }
    floatx4 acc[2][4];
#pragma unroll
    for (int mt = 0; mt < 2; ++mt)
#pragma unroll
        for (int nt = 0; nt < 4; ++nt)
            acc[mt][nt] = (floatx4){0.f, 0.f, 0.f, 0.f};

    for (int k0 = 0; k0 < K; k0 += 32) {
        const float* base; int stride, off;
        if (k0 < 64)       { base = c1; stride = 64;  off = 0; }
        else if (k0 < 128) { base = c2; stride = 64;  off = 64; }
        else if (k0 < 256) { base = c3; stride = 128; off = 128; }
        else               { base = c4; stride = 256; off = 256; }
#pragma unroll
        for (int it = 0; it < 4; ++it) {           // A: 128x32 fp32 -> f16
            int i = t + it * 256;
            int r = i >> 3, seg = (i & 7) * 4;
            float4 av = *(const float4*)(base + (row0 + r) * stride + (k0 - off) + seg);
            half4v h;
            h[0] = (_Float16)av.x; h[1] = (_Float16)av.y;
            h[2] = (_Float16)av.z; h[3] = (_Float16)av.w;
            *(half4v*)&Asm[r][seg] = h;
        }
#pragma unroll
        for (int it = 0; it < 2; ++it) {           // B: 64x32
            int i = t + it * 256;
            int n = i >> 3, seg = (i & 7) * 4;
            float4 bv = *(const float4*)(W + (size_t)(col0 + n) * K + k0 + seg);
            half4v h;
            h[0] = (_Float16)bv.x; h[1] = (_Float16)bv.y;
            h[2] = (_Float16)bv.z; h[3] = (_Float16)bv.w;
            *(half4v*)&Bsm[n][seg] = h;
        }
        __syncthreads();
        half8 af[2], bf[4];
#pragma unroll
        for (int mt = 0; mt < 2; ++mt)
            af[mt] = *(const half8*)&Asm[w * 32 + mt * 16 + l16][quad * 8];
#pragma unroll
        for (int nt = 0; nt < 4; ++nt)
            bf[nt] = *(const half8*)&Bsm[nt * 16 + l16][quad * 8];
#pragma unroll
        for (int mt = 0; mt < 2; ++mt)
#pragma unroll
            for (int nt = 0; nt < 4; ++nt)
                acc[mt][nt] = __builtin_amdgcn_mfma_f32_16x16x32_f16(
                    af[mt], bf[nt], acc[mt][nt], 0, 0, 0);
        __syncthreads();
    }
#pragma unroll
    for (int mt = 0; mt < 2; ++mt)
#pragma unroll
        for (int nt = 0; nt < 4; ++nt)
#pragma unroll
            for (int r = 0; r < 4; ++r) {
                size_t row = row0 + w * 32 + mt * 16 + quad * 4 + r;
                Y[row * Nout + col0 + nt * 16 + l16] = acc[mt][nt][r];
            }
#pragma unroll
    for (int nt = 0; nt < 4; ++nt) {
        float s = 0.f, q = 0.f;
#pragma unroll
        for (int mt = 0; mt < 2; ++mt)
#pragma unroll
            for (int r = 0; r < 4; ++r) {
                float v = acc[mt][nt][r];
                s += v; q += v * v;
            }
        s += __shfl_xor(s, 16); q += __shfl_xor(q, 16);
        s += __shfl_xor(s, 32); q += __shfl_xor(q, 32);
        if (quad == 0) {
            atomicAdd(&colsum[nt * 16 + l16], s);
            atomicAdd(&colsq[nt * 16 + l16], q);
        }
    }
    __syncthreads();
    int bucket = blockIdx.x & 63;
    if (t < 64) {
        atomicAdd(&st[(size_t)bucket * 2 * Nout + col0 + t], colsum[t]);
        atomicAdd(&st[(size_t)bucket * 2 * Nout + Nout + col0 + t], colsq[t]);
    }
}

// ---------------------------------------------------------------------------
__global__ void finalize_kernel(const float* __restrict__ st,
                                const float* __restrict__ g,
                                const float* __restrict__ bb,
                                float* __restrict__ s, float* __restrict__ tt,
                                int C, float invM)
{
    int c = blockIdx.x * blockDim.x + threadIdx.x;
    if (c >= C) return;
    float sum = 0.f, sq = 0.f;
    for (int bk = 0; bk < 64; ++bk) {
        sum += st[(size_t)bk * 2 * C + c];
        sq  += st[(size_t)bk * 2 * C + C + c];
    }
    float mu  = sum * invM;
    float var = sq * invM - mu * mu;
    float sc  = g[c] * rsqrtf(var + EPSBN);
    s[c]  = sc;
    tt[c] = bb[c] - mu * sc;
}

// ---------------------------------------------------------------------------
__global__ __launch_bounds__(256) void maxk_kernel(const bf16_t* __restrict__ Y,
                                                   const float* __restrict__ s,
                                                   const float* __restrict__ tt,
                                                   float* __restrict__ slab,
                                                   int C, int logC)
{
    int gid = blockIdx.x * 256 + threadIdx.x;
    int c = gid & (C - 1);
    int bn = gid >> logC;
    float sc = s[c], tc = tt[c];
    const bf16_t* p = Y + (size_t)bn * KNN * C + c;
    float m = -1e30f;
#pragma unroll
    for (int kk = 0; kk < KNN; ++kk) {
        float v = fmaf(bf2f(p[(size_t)kk * C]), sc, tc);
        m = fmaxf(m, lrelu(v));
    }
    slab[(size_t)bn * C + c] = m;
}

// ---------------------------------------------------------------------------
__global__ __launch_bounds__(256) void out_kernel(const float* __restrict__ y5,
                                                  const float* __restrict__ s,
                                                  const float* __restrict__ tt,
                                                  float* __restrict__ out)
{
    __shared__ float tile[32][65];
    int t = threadIdx.x;
    int b = blockIdx.z;
    int o0 = blockIdx.y * 32;
    int n0 = blockIdx.x * 64;
#pragma unroll
    for (int p = 0; p < 8; ++p) {
        int ol = t & 31, nl = (t >> 5) + 8 * p;
        tile[ol][nl] = y5[((size_t)b * NPTS + n0 + nl) * 1024 + o0 + ol];
    }
    __syncthreads();
#pragma unroll
    for (int p = 0; p < 8; ++p) {
        int nl = t & 63, ol = (t >> 6) + 4 * p;
        float v = fmaf(tile[ol][nl], s[o0 + ol], tt[o0 + ol]);
        out[(size_t)b * 1024 * NPTS + (size_t)(o0 + ol) * NPTS + n0 + nl] = lrelu(v);
    }
}

// ---------------------------------------------------------------------------
extern "C" void kernel_launch(void* const* d_in, const int* in_sizes, int n_in,
                              void* d_out, int out_size, void* d_ws, size_t ws_size,
                              hipStream_t stream)
{
    const float* x  = (const float*)d_in[0];
    const float* W1 = (const float*)d_in[1];
    const float* g1 = (const float*)d_in[2];  const float* b1 = (const float*)d_in[3];
    const float* W2 = (const float*)d_in[4];
    const float* g2 = (const float*)d_in[5];  const float* b2 = (const float*)d_in[6];
    const float* W3 = (const float*)d_in[7];
    const float* g3 = (const float*)d_in[8];  const float* b3 = (const float*)d_in[9];
    const float* W4 = (const float*)d_in[10];
    const float* g4 = (const float*)d_in[11]; const float* b4 = (const float*)d_in[12];
    const float* W5 = (const float*)d_in[13];
    const float* g5 = (const float*)d_in[14]; const float* b5 = (const float*)d_in[15];
    float* out = (float*)d_out;

    // -------- workspace layout (~194 MB total) --------
    char* p = (char*)d_ws;
    int* idx = (int*)p;                 p += (size_t)M1 * 4;                 // 1.3 MB
    bf16_t* y1 = (bf16_t*)p;
    float*  y5 = (float*)p;             p += (size_t)M1 * 64 * 2;           // arena A
    bf16_t* y2 = (bf16_t*)p;            p += (size_t)M1 * 64 * 2;
    bf16_t* y3 = (bf16_t*)p;            p += (size_t)M1 * 128 * 2;
    float* c1 = (float*)p;              p += (size_t)M5 * 64 * 4;
    float* c2 = (float*)p;              p += (size_t)M5 * 64 * 4;
    float* c3 = (float*)p;              p += (size_t)M5 * 128 * 4;
    float* c4 = (float*)p;              p += (size_t)M5 * 256 * 4;
    float* st1 = (float*)p;             p += 64 * 2 * 64 * 4;
    float* st2 = (float*)p;             p += 64 * 2 * 64 * 4;
    float* st3 = (float*)p;             p += 64 * 2 * 128 * 4;
    float* st4 = (float*)p;             p += 64 * 2 * 256 * 4;
    float* st5 = (float*)p;             p += 64 * 2 * 1024 * 4;
    float* s1 = (float*)p; p += 64 * 4;   float* t1 = (float*)p; p += 64 * 4;
    float* s2 = (float*)p; p += 64 * 4;   float* t2 = (float*)p; p += 64 * 4;
    float* s3 = (float*)p; p += 128 * 4;  float* t3 = (float*)p; p += 128 * 4;
    float* s4 = (float*)p; p += 256 * 4;  float* t4 = (float*)p; p += 256 * 4;
    float* s5 = (float*)p; p += 1024 * 4; float* t5 = (float*)p; p += 1024 * 4;

    size_t statsBytes = (size_t)(64 * 2 * (64 + 64 + 128 + 256 + 1024)) * 4;
    hipMemsetAsync(st1, 0, statsBytes, stream);

    const float invM14 = 1.0f / (float)M1;
    const float invM5  = 1.0f / (float)M5;

    knn_kernel<<<M5 / 4, 256, 0, stream>>>(x, idx);

    // stage 1
    conv1_kernel<<<M1 / 64, 256, 0, stream>>>(x, idx, W1, y1, st1);
    finalize_kernel<<<1, 256, 0, stream>>>(st1, g1, b1, s1, t1, 64, invM14);
    maxk_kernel<<<(M5 * 64) / 256, 256, 0, stream>>>(y1, s1, t1, c1, 64, 6);

    // stage 2
    gemm_mfma_bn<<<dim3(M1 / 128, 1), 256, 0, stream>>>(y1, W2, s1, t1, y2, st2, 64, 64);
    finalize_kernel<<<1, 256, 0, stream>>>(st2, g2, b2, s2, t2, 64, invM14);
    maxk_kernel<<<(M5 * 64) / 256, 256, 0, stream>>>(y2, s2, t2, c2, 64, 6);

    // stage 3
    gemm_mfma_bn<<<dim3(M1 / 128, 2), 256, 0, stream>>>(y2, W3, s2, t2, y3, st3, 64, 128);
    finalize_kernel<<<1, 256, 0, stream>>>(st3, g3, b3, s3, t3, 128, invM14);
    maxk_kernel<<<(M5 * 128) / 256, 256, 0, stream>>>(y3, s3, t3, c3, 128, 7);

    // stage 4: pass 1 = stats only, pass 2 = fused BN+max (identical FP order)
    gemm_mfma_bn<<<dim3(M1 / 128, 4), 256, 0, stream>>>(y3, W4, s3, t3, (bf16_t*)nullptr, st4, 128, 256);
    finalize_kernel<<<1, 256, 0, stream>>>(st4, g4, b4, s4, t4, 256, invM14);
    gemm4_mfma<<<dim3(M1 / 320, 4), 256, 0, stream>>>(y3, W4, s3, t3, s4, t4, c4);

    // stage 5
    gemm5_mfma<<<dim3(M5 / 128, 16), 256, 0, stream>>>(c1, c2, c3, c4, W5, y5, st5);
    finalize_kernel<<<4, 256, 0, stream>>>(st5, g5, b5, s5, t5, 1024, invM5);

    out_kernel<<<dim3(NPTS / 64, 1024 / 32, BATCH), 256, 0, stream>>>(y5, s5, t5, out);
}

// Round 6
// 579.701 us; speedup vs baseline: 6.1052x; 1.1218x over previous
//
#include <hip/hip_runtime.h>

#define BATCH 8
#define NPTS  2048
#define KNN   20
#define M1    (BATCH * NPTS * KNN)   // 327680 rows for conv stages
#define M5    (BATCH * NPTS)         // 16384 rows for final projection
#define EPSBN 1e-5f
#define LDA   40                      // padded LDS k-stride (halfs): 2-way max aliasing

typedef unsigned short bf16_t;
typedef _Float16 half8 __attribute__((ext_vector_type(8)));
typedef _Float16 half4v __attribute__((ext_vector_type(4)));
typedef float    floatx4 __attribute__((ext_vector_type(4)));

__device__ __forceinline__ float bf2f(bf16_t u) {
    return __uint_as_float(((unsigned int)u) << 16);
}
__device__ __forceinline__ bf16_t f2bf(float f) {
    unsigned int u = __float_as_uint(f);
    return (bf16_t)((u + 0x7fffu + ((u >> 16) & 1u)) >> 16);
}
__device__ __forceinline__ float lrelu(float v) { return v >= 0.f ? v : 0.2f * v; }

// ---------------------------------------------------------------------------
// KNN v3 — one wave per point, 8 points/block (512 thr), 32 KB LDS.
// Exact fp32 reference arithmetic (bit-identical to numpy):
//   inner=(x0n*x0m+x1n*x1m)+x2n*x2m; xx=(x0^2+x1^2)+x2^2; d=(2*inner-xxn)-xxm
// Coords interleaved float4 (x0,x1,x2,xx): 1 ds_read_b128 per candidate.
// Per-lane top-2 packed keys in regs + 32-bit extracted-slot mask; rare
// rebuild recomputes distances (no keys array -> half the LDS, 3-4x waves).
// ---------------------------------------------------------------------------
__global__ __launch_bounds__(512, 6) void knn_kernel(const float* __restrict__ x,
                                                     int* __restrict__ idx)
{
    __shared__ float4 pts[NPTS];              // 32 KB
    int t = threadIdx.x;
    int b = blockIdx.x >> 8;                  // 256 blocks per batch
    int base = (blockIdx.x & 255) * 8;        // 8 points per block (1/wave)
    const float* xb = x + (size_t)b * 3 * NPTS;
    for (int i = t; i < NPTS; i += 512) {
        float a0 = xb[i], a1 = xb[NPTS + i], a2 = xb[2 * NPTS + i];
        float xx = __fadd_rn(__fadd_rn(__fmul_rn(a0, a0), __fmul_rn(a1, a1)),
                             __fmul_rn(a2, a2));
        pts[i] = make_float4(a0, a1, a2, xx);
    }
    __syncthreads();
    int w = t >> 6, lane = t & 63;
    int n = base + w;
    float4 pn = pts[n];
    float xn0 = pn.x, xn1 = pn.y, xn2 = pn.z, xxn = pn.w;
    unsigned long long k1 = 0ULL, k2 = 0ULL;  // 0 < any real packed key
    unsigned int emask = 0u;                  // extracted slots (j index)
#pragma unroll 4
    for (int j = 0; j < NPTS / 64; ++j) {
        int m = j * 64 + lane;
        float4 pm = pts[m];
        float inner = __fadd_rn(__fadd_rn(__fmul_rn(xn0, pm.x),
                                          __fmul_rn(xn1, pm.y)),
                                __fmul_rn(xn2, pm.z));
        float d = __fsub_rn(__fsub_rn(__fmul_rn(2.0f, inner), xxn), pm.w);
        unsigned int u = __float_as_uint(d);
        unsigned int s = u ^ ((u >> 31) ? 0xFFFFFFFFu : 0x80000000u);
        unsigned long long kp = ((unsigned long long)s << 11)
                              | (unsigned int)(NPTS - 1 - m);
        if (kp > k1)      { k2 = k1; k1 = kp; }
        else if (kp > k2) { k2 = kp; }
    }
    int* op = idx + (size_t)(b * NPTS + n) * KNN;
    for (int r = 0; r < KNN; ++r) {
        unsigned long long km = k1;
#pragma unroll
        for (int off = 32; off > 0; off >>= 1) {
            unsigned long long o = __shfl_xor(km, off);
            km = o > km ? o : km;
        }
        int m_ex = NPTS - 1 - (int)(km & 0x7FFULL);
        if (lane == 0) op[r] = m_ex;
        if ((m_ex & 63) == lane) {            // owner lane updates its top-2
            emask |= 1u << (m_ex >> 6);
            if (k2 != 0ULL) { k1 = k2; k2 = 0ULL; }
            else {                             // rare: recompute survivors
                k1 = 0ULL; k2 = 0ULL;
                for (int j = 0; j < NPTS / 64; ++j) {
                    if (emask & (1u << j)) continue;
                    int m = j * 64 + lane;
                    float4 pm = pts[m];
                    float inner = __fadd_rn(__fadd_rn(__fmul_rn(xn0, pm.x),
                                                      __fmul_rn(xn1, pm.y)),
                                            __fmul_rn(xn2, pm.z));
                    float d = __fsub_rn(__fsub_rn(__fmul_rn(2.0f, inner), xxn),
                                        pm.w);
                    unsigned int u = __float_as_uint(d);
                    unsigned int s = u ^ ((u >> 31) ? 0xFFFFFFFFu : 0x80000000u);
                    unsigned long long kp = ((unsigned long long)s << 11)
                                          | (unsigned int)(NPTS - 1 - m);
                    if (kp > k1)      { k2 = k1; k1 = kp; }
                    else if (kp > k2) { k2 = kp; }
                }
            }
        }
    }
}

// ---------------------------------------------------------------------------
// conv1 (unchanged): edge features * W1 -> y1 bf16 + stats
// ---------------------------------------------------------------------------
__global__ __launch_bounds__(256) void conv1_kernel(const float* __restrict__ x,
                                                    const int* __restrict__ idx,
                                                    const float* __restrict__ W1,
                                                    bf16_t* __restrict__ Y,
                                                    float* __restrict__ st)
{
    __shared__ float f[64][6];
    __shared__ float w[384];
    __shared__ float red[256];
    int t = threadIdx.x;
    for (int i = t; i < 384; i += 256) w[i] = W1[i];
    int row0 = blockIdx.x * 64;
    if (t < 64) {
        int gr = row0 + t;
        int bn = gr / KNN;
        int j = idx[gr];
        int b = bn >> 11, n = bn & (NPTS - 1);
        const float* xb = x + (size_t)b * 3 * NPTS;
        float xi0 = xb[n], xi1 = xb[NPTS + n], xi2 = xb[2 * NPTS + n];
        float xj0 = xb[j], xj1 = xb[NPTS + j], xj2 = xb[2 * NPTS + j];
        f[t][0] = xj0 - xi0; f[t][1] = xj1 - xi1; f[t][2] = xj2 - xi2;
        f[t][3] = xi0;       f[t][4] = xi1;       f[t][5] = xi2;
    }
    __syncthreads();
    int tx = t & 63, ty = t >> 6;
    float wc0 = w[tx * 6 + 0], wc1 = w[tx * 6 + 1], wc2 = w[tx * 6 + 2];
    float wc3 = w[tx * 6 + 3], wc4 = w[tx * 6 + 4], wc5 = w[tx * 6 + 5];
    float ssum = 0.f, ssq = 0.f;
#pragma unroll
    for (int i = 0; i < 16; ++i) {
        int r = ty * 16 + i;
        float yv = f[r][0] * wc0 + f[r][1] * wc1 + f[r][2] * wc2 +
                   f[r][3] * wc3 + f[r][4] * wc4 + f[r][5] * wc5;
        Y[(size_t)(row0 + r) * 64 + tx] = f2bf(yv);
        ssum += yv; ssq += yv * yv;
    }
    int bucket = blockIdx.x & 63;
    red[ty * 64 + tx] = ssum;
    __syncthreads();
    if (t < 64) {
        float v = red[t] + red[64 + t] + red[128 + t] + red[192 + t];
        atomicAdd(&st[bucket * 128 + t], v);
    }
    __syncthreads();
    red[ty * 64 + tx] = ssq;
    __syncthreads();
    if (t < 64) {
        float v = red[t] + red[64 + t] + red[128 + t] + red[192 + t];
        atomicAdd(&st[bucket * 128 + 64 + t], v);
    }
}

// ---------------------------------------------------------------------------
// MFMA GEMM (s2/s3/s4-stats): Y[M,Nout] = act(A)[M,K] * W[Nout,K]^T
// A bf16; act = lrelu(a*sIn+tIn) applied in staging, rounded to fp16.
// W fp32 -> fp16 in staging. 16x16x32_f16 MFMA, fp32 accumulate.
// Tile 128x64, BK=32, 256 thr (4 waves x 32 rows). Y optional (bf16).
// ---------------------------------------------------------------------------
__global__ __launch_bounds__(256) void gemm_mfma_bn(const bf16_t* __restrict__ A,
                                                    const float* __restrict__ W,
                                                    const float* __restrict__ sIn,
                                                    const float* __restrict__ tIn,
                                                    bf16_t* __restrict__ Y,
                                                    float* __restrict__ st,
                                                    int K, int Nout)
{
    __shared__ _Float16 Asm[128][LDA];
    __shared__ _Float16 Bsm[64][LDA];
    __shared__ float colsum[64], colsq[64];
    int t = threadIdx.x;
    int lane = t & 63, w = t >> 6;
    int quad = lane >> 4, l16 = lane & 15;
    size_t row0 = (size_t)blockIdx.x * 128;
    int col0 = blockIdx.y * 64;
    if (t < 64) { colsum[t] = 0.f; colsq[t] = 0.f; }
    floatx4 acc[2][4];
#pragma unroll
    for (int mt = 0; mt < 2; ++mt)
#pragma unroll
        for (int nt = 0; nt < 4; ++nt)
            acc[mt][nt] = (floatx4){0.f, 0.f, 0.f, 0.f};

    for (int k0 = 0; k0 < K; k0 += 32) {
#pragma unroll
        for (int it = 0; it < 2; ++it) {           // A: 128x32 bf16 -> act -> f16
            int i = t + it * 256;
            int r = i >> 2, ko = (i & 3) * 8;
            uint4 au = *(const uint4*)(A + (row0 + r) * K + k0 + ko);
            float4 sv0 = *(const float4*)(sIn + k0 + ko);
            float4 sv1 = *(const float4*)(sIn + k0 + ko + 4);
            float4 tv0 = *(const float4*)(tIn + k0 + ko);
            float4 tv1 = *(const float4*)(tIn + k0 + ko + 4);
            half8 hv;
            hv[0] = (_Float16)lrelu(fmaf(bf2f(au.x & 0xffff), sv0.x, tv0.x));
            hv[1] = (_Float16)lrelu(fmaf(bf2f(au.x >> 16),    sv0.y, tv0.y));
            hv[2] = (_Float16)lrelu(fmaf(bf2f(au.y & 0xffff), sv0.z, tv0.z));
            hv[3] = (_Float16)lrelu(fmaf(bf2f(au.y >> 16),    sv0.w, tv0.w));
            hv[4] = (_Float16)lrelu(fmaf(bf2f(au.z & 0xffff), sv1.x, tv1.x));
            hv[5] = (_Float16)lrelu(fmaf(bf2f(au.z >> 16),    sv1.y, tv1.y));
            hv[6] = (_Float16)lrelu(fmaf(bf2f(au.w & 0xffff), sv1.z, tv1.z));
            hv[7] = (_Float16)lrelu(fmaf(bf2f(au.w >> 16),    sv1.w, tv1.w));
            *(half8*)&Asm[r][ko] = hv;
        }
#pragma unroll
        for (int it = 0; it < 2; ++it) {           // B: 64x32 fp32 -> f16
            int i = t + it * 256;
            int n = i >> 3, seg = (i & 7) * 4;
            float4 bv = *(const float4*)(W + (size_t)(col0 + n) * K + k0 + seg);
            half4v h;
            h[0] = (_Float16)bv.x; h[1] = (_Float16)bv.y;
            h[2] = (_Float16)bv.z; h[3] = (_Float16)bv.w;
            *(half4v*)&Bsm[n][seg] = h;
        }
        __syncthreads();
        half8 af[2], bf[4];
#pragma unroll
        for (int mt = 0; mt < 2; ++mt)
            af[mt] = *(const half8*)&Asm[w * 32 + mt * 16 + l16][quad * 8];
#pragma unroll
        for (int nt = 0; nt < 4; ++nt)
            bf[nt] = *(const half8*)&Bsm[nt * 16 + l16][quad * 8];
#pragma unroll
        for (int mt = 0; mt < 2; ++mt)
#pragma unroll
            for (int nt = 0; nt < 4; ++nt)
                acc[mt][nt] = __builtin_amdgcn_mfma_f32_16x16x32_f16(
                    af[mt], bf[nt], acc[mt][nt], 0, 0, 0);
        __syncthreads();
    }
    if (Y) {
#pragma unroll
        for (int mt = 0; mt < 2; ++mt)
#pragma unroll
            for (int nt = 0; nt < 4; ++nt)
#pragma unroll
                for (int r = 0; r < 4; ++r) {
                    size_t row = row0 + w * 32 + mt * 16 + quad * 4 + r;
                    Y[row * Nout + col0 + nt * 16 + l16] = f2bf(acc[mt][nt][r]);
                }
    }
#pragma unroll
    for (int nt = 0; nt < 4; ++nt) {
        float s = 0.f, q = 0.f;
#pragma unroll
        for (int mt = 0; mt < 2; ++mt)
#pragma unroll
            for (int r = 0; r < 4; ++r) {
                float v = acc[mt][nt][r];
                s += v; q += v * v;
            }
        s += __shfl_xor(s, 16); q += __shfl_xor(q, 16);
        s += __shfl_xor(s, 32); q += __shfl_xor(q, 32);
        if (quad == 0) {
            atomicAdd(&colsum[nt * 16 + l16], s);
            atomicAdd(&colsq[nt * 16 + l16], q);
        }
    }
    __syncthreads();
    int bucket = blockIdx.x & 63;
    if (t < 64) {
        atomicAdd(&st[(size_t)bucket * 2 * Nout + col0 + t], colsum[t]);
        atomicAdd(&st[(size_t)bucket * 2 * Nout + Nout + col0 + t], colsq[t]);
    }
}

// ---------------------------------------------------------------------------
// Stage-4 fused pass 2 (MFMA): BM=320 rows = 16 points; computes y4 tile,
// BN+LReLU, max-over-k via LDS, writes slab4 [M5,256]. K=128.
// ---------------------------------------------------------------------------
__global__ __launch_bounds__(256) void gemm4_mfma(const bf16_t* __restrict__ A,
                                                  const float* __restrict__ W,
                                                  const float* __restrict__ s3,
                                                  const float* __restrict__ t3,
                                                  const float* __restrict__ s4,
                                                  const float* __restrict__ t4,
                                                  float* __restrict__ slab4)
{
    const int K = 128;
    __shared__ _Float16 Asm[320][LDA];     // 25.6 KB
    __shared__ _Float16 Bsm[64][LDA];      //  5.1 KB
    __shared__ _Float16 tile[320][72];     // 46.1 KB
    int t = threadIdx.x;
    int lane = t & 63, w = t >> 6;
    int quad = lane >> 4, l16 = lane & 15;
    size_t row0 = (size_t)blockIdx.x * 320;
    int col0 = blockIdx.y * 64;
    floatx4 acc[5][4];
#pragma unroll
    for (int mt = 0; mt < 5; ++mt)
#pragma unroll
        for (int nt = 0; nt < 4; ++nt)
            acc[mt][nt] = (floatx4){0.f, 0.f, 0.f, 0.f};

    for (int k0 = 0; k0 < K; k0 += 32) {
#pragma unroll
        for (int it = 0; it < 5; ++it) {           // A: 320x32
            int i = t + it * 256;
            int r = i >> 2, ko = (i & 3) * 8;
            uint4 au = *(const uint4*)(A + (row0 + r) * K + k0 + ko);
            float4 sv0 = *(const float4*)(s3 + k0 + ko);
            float4 sv1 = *(const float4*)(s3 + k0 + ko + 4);
            float4 tv0 = *(const float4*)(t3 + k0 + ko);
            float4 tv1 = *(const float4*)(t3 + k0 + ko + 4);
            half8 hv;
            hv[0] = (_Float16)lrelu(fmaf(bf2f(au.x & 0xffff), sv0.x, tv0.x));
            hv[1] = (_Float16)lrelu(fmaf(bf2f(au.x >> 16),    sv0.y, tv0.y));
            hv[2] = (_Float16)lrelu(fmaf(bf2f(au.y & 0xffff), sv0.z, tv0.z));
            hv[3] = (_Float16)lrelu(fmaf(bf2f(au.y >> 16),    sv0.w, tv0.w));
            hv[4] = (_Float16)lrelu(fmaf(bf2f(au.z & 0xffff), sv1.x, tv1.x));
            hv[5] = (_Float16)lrelu(fmaf(bf2f(au.z >> 16),    sv1.y, tv1.y));
            hv[6] = (_Float16)lrelu(fmaf(bf2f(au.w & 0xffff), sv1.z, tv1.z));
            hv[7] = (_Float16)lrelu(fmaf(bf2f(au.w >> 16),    sv1.w, tv1.w));
            *(half8*)&Asm[r][ko] = hv;
        }
#pragma unroll
        for (int it = 0; it < 2; ++it) {           // B: 64x32
            int i = t + it * 256;
            int n = i >> 3, seg = (i & 7) * 4;
            float4 bv = *(const float4*)(W + (size_t)(col0 + n) * K + k0 + seg);
            half4v h;
            h[0] = (_Float16)bv.x; h[1] = (_Float16)bv.y;
            h[2] = (_Float16)bv.z; h[3] = (_Float16)bv.w;
            *(half4v*)&Bsm[n][seg] = h;
        }
        __syncthreads();
        half8 af[5], bf[4];
#pragma unroll
        for (int mt = 0; mt < 5; ++mt)
            af[mt] = *(const half8*)&Asm[w * 80 + mt * 16 + l16][quad * 8];
#pragma unroll
        for (int nt = 0; nt < 4; ++nt)
            bf[nt] = *(const half8*)&Bsm[nt * 16 + l16][quad * 8];
#pragma unroll
        for (int mt = 0; mt < 5; ++mt)
#pragma unroll
            for (int nt = 0; nt < 4; ++nt)
                acc[mt][nt] = __builtin_amdgcn_mfma_f32_16x16x32_f16(
                    af[mt], bf[nt], acc[mt][nt], 0, 0, 0);
        __syncthreads();
    }
    float s4c[4], t4c[4];
#pragma unroll
    for (int nt = 0; nt < 4; ++nt) {
        s4c[nt] = s4[col0 + nt * 16 + l16];
        t4c[nt] = t4[col0 + nt * 16 + l16];
    }
#pragma unroll
    for (int mt = 0; mt < 5; ++mt)
#pragma unroll
        for (int nt = 0; nt < 4; ++nt)
#pragma unroll
            for (int r = 0; r < 4; ++r) {
                int rl = w * 80 + mt * 16 + quad * 4 + r;
                tile[rl][nt * 16 + l16] =
                    (_Float16)lrelu(fmaf(acc[mt][nt][r], s4c[nt], t4c[nt]));
            }
    __syncthreads();
    int col = t & 63;
#pragma unroll
    for (int g = 0; g < 4; ++g) {
        int pt = (t >> 6) * 4 + g;                 // 0..15
        float m = -1e30f;
#pragma unroll
        for (int k = 0; k < KNN; ++k)
            m = fmaxf(m, (float)tile[pt * KNN + k][col]);
        slab4[((size_t)blockIdx.x * 16 + pt) * 256 + col0 + col] = m;
    }
}

// ---------------------------------------------------------------------------
// Final GEMM (MFMA): y5[M5,1024] = cat[M5,512]*W5^T; cat gathered fp32->f16.
// ---------------------------------------------------------------------------
__global__ __launch_bounds__(256) void gemm5_mfma(const float* __restrict__ c1,
                                                  const float* __restrict__ c2,
                                                  const float* __restrict__ c3,
                                                  const float* __restrict__ c4,
                                                  const float* __restrict__ W,
                                                  float* __restrict__ Y,
                                                  float* __restrict__ st)
{
    const int K = 512, Nout = 1024;
    __shared__ _Float16 Asm[128][LDA];
    __shared__ _Float16 Bsm[64][LDA];
    __shared__ float colsum[64], colsq[64];
    int t = threadIdx.x;
    int lane = t & 63, w = t >> 6;
    int quad = lane >> 4, l16 = lane & 15;
    size_t row0 = (size_t)blockIdx.x * 128;
    int col0 = blockIdx.y * 64;
    if (t < 64) { colsum[t] = 0.f; colsq[t] = 0.f; }
    floatx4 acc[2][4];
#pragma unroll
    for (int mt = 0; mt < 2; ++mt)
#pragma unroll
        for (int nt = 0; nt < 4; ++nt)
            acc[mt][nt] = (floatx4){0.f, 0.f, 0.f, 0.f};

    for (int k0 = 0; k0 < K; k0 += 32) {
        const float* base; int stride, off;
        if (k0 < 64)       { base = c1; stride = 64;  off = 0; }
        else if (k0 < 128) { base = c2; stride = 64;  off = 64; }
        else if (k0 < 256) { base = c3; stride = 128; off = 128; }
        else               { base = c4; stride = 256; off = 256; }
#pragma unroll
        for (int it = 0; it < 4; ++it) {           // A: 128x32 fp32 -> f16
            int i = t + it * 256;
            int r = i >> 3, seg = (i & 7) * 4;
            float4 av = *(const float4*)(base + (row0 + r) * stride + (k0 - off) + seg);
            half4v h;
            h[0] = (_Float16)av.x; h[1] = (_Float16)av.y;
            h[2] = (_Float16)av.z; h[3] = (_Float16)av.w;
            *(half4v*)&Asm[r][seg] = h;
        }
#pragma unroll
        for (int it = 0; it < 2; ++it) {           // B: 64x32
            int i = t + it * 256;
            int n = i >> 3, seg = (i & 7) * 4;
            float4 bv = *(const float4*)(W + (size_t)(col0 + n) * K + k0 + seg);
            half4v h;
            h[0] = (_Float16)bv.x; h[1] = (_Float16)bv.y;
            h[2] = (_Float16)bv.z; h[3] = (_Float16)bv.w;
            *(half4v*)&Bsm[n][seg] = h;
        }
        __syncthreads();
        half8 af[2], bf[4];
#pragma unroll
        for (int mt = 0; mt < 2; ++mt)
            af[mt] = *(const half8*)&Asm[w * 32 + mt * 16 + l16][quad * 8];
#pragma unroll
        for (int nt = 0; nt < 4; ++nt)
            bf[nt] = *(const half8*)&Bsm[nt * 16 + l16][quad * 8];
#pragma unroll
        for (int mt = 0; mt < 2; ++mt)
#pragma unroll
            for (int nt = 0; nt < 4; ++nt)
                acc[mt][nt] = __builtin_amdgcn_mfma_f32_16x16x32_f16(
                    af[mt], bf[nt], acc[mt][nt], 0, 0, 0);
        __syncthreads();
    }
#pragma unroll
    for (int mt = 0; mt < 2; ++mt)
#pragma unroll
        for (int nt = 0; nt < 4; ++nt)
#pragma unroll
            for (int r = 0; r < 4; ++r) {
                size_t row = row0 + w * 32 + mt * 16 + quad * 4 + r;
                Y[row * Nout + col0 + nt * 16 + l16] = acc[mt][nt][r];
            }
#pragma unroll
    for (int nt = 0; nt < 4; ++nt) {
        float s = 0.f, q = 0.f;
#pragma unroll
        for (int mt = 0; mt < 2; ++mt)
#pragma unroll
            for (int r = 0; r < 4; ++r) {
                float v = acc[mt][nt][r];
                s += v; q += v * v;
            }
        s += __shfl_xor(s, 16); q += __shfl_xor(q, 16);
        s += __shfl_xor(s, 32); q += __shfl_xor(q, 32);
        if (quad == 0) {
            atomicAdd(&colsum[nt * 16 + l16], s);
            atomicAdd(&colsq[nt * 16 + l16], q);
        }
    }
    __syncthreads();
    int bucket = blockIdx.x & 63;
    if (t < 64) {
        atomicAdd(&st[(size_t)bucket * 2 * Nout + col0 + t], colsum[t]);
        atomicAdd(&st[(size_t)bucket * 2 * Nout + Nout + col0 + t], colsq[t]);
    }
}

// ---------------------------------------------------------------------------
__global__ void finalize_kernel(const float* __restrict__ st,
                                const float* __restrict__ g,
                                const float* __restrict__ bb,
                                float* __restrict__ s, float* __restrict__ tt,
                                int C, float invM)
{
    int c = blockIdx.x * blockDim.x + threadIdx.x;
    if (c >= C) return;
    float sum = 0.f, sq = 0.f;
    for (int bk = 0; bk < 64; ++bk) {
        sum += st[(size_t)bk * 2 * C + c];
        sq  += st[(size_t)bk * 2 * C + C + c];
    }
    float mu  = sum * invM;
    float var = sq * invM - mu * mu;
    float sc  = g[c] * rsqrtf(var + EPSBN);
    s[c]  = sc;
    tt[c] = bb[c] - mu * sc;
}

// ---------------------------------------------------------------------------
__global__ __launch_bounds__(256) void maxk_kernel(const bf16_t* __restrict__ Y,
                                                   const float* __restrict__ s,
                                                   const float* __restrict__ tt,
                                                   float* __restrict__ slab,
                                                   int C, int logC)
{
    int gid = blockIdx.x * 256 + threadIdx.x;
    int c = gid & (C - 1);
    int bn = gid >> logC;
    float sc = s[c], tc = tt[c];
    const bf16_t* p = Y + (size_t)bn * KNN * C + c;
    float m = -1e30f;
#pragma unroll
    for (int kk = 0; kk < KNN; ++kk) {
        float v = fmaf(bf2f(p[(size_t)kk * C]), sc, tc);
        m = fmaxf(m, lrelu(v));
    }
    slab[(size_t)bn * C + c] = m;
}

// ---------------------------------------------------------------------------
__global__ __launch_bounds__(256) void out_kernel(const float* __restrict__ y5,
                                                  const float* __restrict__ s,
                                                  const float* __restrict__ tt,
                                                  float* __restrict__ out)
{
    __shared__ float tile[32][65];
    int t = threadIdx.x;
    int b = blockIdx.z;
    int o0 = blockIdx.y * 32;
    int n0 = blockIdx.x * 64;
#pragma unroll
    for (int p = 0; p < 8; ++p) {
        int ol = t & 31, nl = (t >> 5) + 8 * p;
        tile[ol][nl] = y5[((size_t)b * NPTS + n0 + nl) * 1024 + o0 + ol];
    }
    __syncthreads();
#pragma unroll
    for (int p = 0; p < 8; ++p) {
        int nl = t & 63, ol = (t >> 6) + 4 * p;
        float v = fmaf(tile[ol][nl], s[o0 + ol], tt[o0 + ol]);
        out[(size_t)b * 1024 * NPTS + (size_t)(o0 + ol) * NPTS + n0 + nl] = lrelu(v);
    }
}

// ---------------------------------------------------------------------------
extern "C" void kernel_launch(void* const* d_in, const int* in_sizes, int n_in,
                              void* d_out, int out_size, void* d_ws, size_t ws_size,
                              hipStream_t stream)
{
    const float* x  = (const float*)d_in[0];
    const float* W1 = (const float*)d_in[1];
    const float* g1 = (const float*)d_in[2];  const float* b1 = (const float*)d_in[3];
    const float* W2 = (const float*)d_in[4];
    const float* g2 = (const float*)d_in[5];  const float* b2 = (const float*)d_in[6];
    const float* W3 = (const float*)d_in[7];
    const float* g3 = (const float*)d_in[8];  const float* b3 = (const float*)d_in[9];
    const float* W4 = (const float*)d_in[10];
    const float* g4 = (const float*)d_in[11]; const float* b4 = (const float*)d_in[12];
    const float* W5 = (const float*)d_in[13];
    const float* g5 = (const float*)d_in[14]; const float* b5 = (const float*)d_in[15];
    float* out = (float*)d_out;

    // -------- workspace layout (~194 MB total) --------
    char* p = (char*)d_ws;
    int* idx = (int*)p;                 p += (size_t)M1 * 4;                 // 1.3 MB
    bf16_t* y1 = (bf16_t*)p;
    float*  y5 = (float*)p;             p += (size_t)M1 * 64 * 2;           // arena A
    bf16_t* y2 = (bf16_t*)p;            p += (size_t)M1 * 64 * 2;
    bf16_t* y3 = (bf16_t*)p;            p += (size_t)M1 * 128 * 2;
    float* c1 = (float*)p;              p += (size_t)M5 * 64 * 4;
    float* c2 = (float*)p;              p += (size_t)M5 * 64 * 4;
    float* c3 = (float*)p;              p += (size_t)M5 * 128 * 4;
    float* c4 = (float*)p;              p += (size_t)M5 * 256 * 4;
    float* st1 = (float*)p;             p += 64 * 2 * 64 * 4;
    float* st2 = (float*)p;             p += 64 * 2 * 64 * 4;
    float* st3 = (float*)p;             p += 64 * 2 * 128 * 4;
    float* st4 = (float*)p;             p += 64 * 2 * 256 * 4;
    float* st5 = (float*)p;             p += 64 * 2 * 1024 * 4;
    float* s1 = (float*)p; p += 64 * 4;   float* t1 = (float*)p; p += 64 * 4;
    float* s2 = (float*)p; p += 64 * 4;   float* t2 = (float*)p; p += 64 * 4;
    float* s3 = (float*)p; p += 128 * 4;  float* t3 = (float*)p; p += 128 * 4;
    float* s4 = (float*)p; p += 256 * 4;  float* t4 = (float*)p; p += 256 * 4;
    float* s5 = (float*)p; p += 1024 * 4; float* t5 = (float*)p; p += 1024 * 4;

    size_t statsBytes = (size_t)(64 * 2 * (64 + 64 + 128 + 256 + 1024)) * 4;
    hipMemsetAsync(st1, 0, statsBytes, stream);

    const float invM14 = 1.0f / (float)M1;
    const float invM5  = 1.0f / (float)M5;

    knn_kernel<<<M5 / 8, 512, 0, stream>>>(x, idx);

    // stage 1
    conv1_kernel<<<M1 / 64, 256, 0, stream>>>(x, idx, W1, y1, st1);
    finalize_kernel<<<1, 256, 0, stream>>>(st1, g1, b1, s1, t1, 64, invM14);
    maxk_kernel<<<(M5 * 64) / 256, 256, 0, stream>>>(y1, s1, t1, c1, 64, 6);

    // stage 2
    gemm_mfma_bn<<<dim3(M1 / 128, 1), 256, 0, stream>>>(y1, W2, s1, t1, y2, st2, 64, 64);
    finalize_kernel<<<1, 256, 0, stream>>>(st2, g2, b2, s2, t2, 64, invM14);
    maxk_kernel<<<(M5 * 64) / 256, 256, 0, stream>>>(y2, s2, t2, c2, 64, 6);

    // stage 3
    gemm_mfma_bn<<<dim3(M1 / 128, 2), 256, 0, stream>>>(y2, W3, s2, t2, y3, st3, 64, 128);
    finalize_kernel<<<1, 256, 0, stream>>>(st3, g3, b3, s3, t3, 128, invM14);
    maxk_kernel<<<(M5 * 128) / 256, 256, 0, stream>>>(y3, s3, t3, c3, 128, 7);

    // stage 4: pass 1 = stats only, pass 2 = fused BN+max (identical FP order)
    gemm_mfma_bn<<<dim3(M1 / 128, 4), 256, 0, stream>>>(y3, W4, s3, t3, (bf16_t*)nullptr, st4, 128, 256);
    finalize_kernel<<<1, 256, 0, stream>>>(st4, g4, b4, s4, t4, 256, invM14);
    gemm4_mfma<<<dim3(M1 / 320, 4), 256, 0, stream>>>(y3, W4, s3, t3, s4, t4, c4);

    // stage 5
    gemm5_mfma<<<dim3(M5 / 128, 16), 256, 0, stream>>>(c1, c2, c3, c4, W5, y5, st5);
    finalize_kernel<<<4, 256, 0, stream>>>(st5, g5, b5, s5, t5, 1024, invM5);

    out_kernel<<<dim3(NPTS / 64, 1024 / 32, BATCH), 256, 0, stream>>>(y5, s5, t5, out);
}